// Round 1
// baseline (6656.117 us; speedup 1.0000x reference)
//
#include <hip/hip_runtime.h>
#include <hip/hip_bf16.h>
#include <math.h>

// Problem constants
#define B_  4
#define S_  2048
#define D_  512
#define H_  8
#define DH_ 64
#define FF_ 2048
#define L_  4
#define V_  256
#define NTOK (B_ * S_)          // 8192
#define XN  ((size_t)NTOK * D_) // 4,194,304 floats per [B,S,D] buffer

// ---------------------------------------------------------------------------
// Embedding + sinusoidal positional encoding:
// x[b,s,d] = emb[tok[b,s], d] * sqrt(D) + pe(s, d)
// pe(s,2k) = sin(s * exp(-2k*ln(10000)/D)); pe(s,2k+1) = cos(same)
// ---------------------------------------------------------------------------
__global__ void embed_kernel(const int* __restrict__ tok,
                             const float* __restrict__ emb,
                             float* __restrict__ X) {
    int bs = blockIdx.x;              // 0..NTOK-1
    int s = bs % S_;
    int t = tok[bs];
    const float scale = 22.62741699796952f; // sqrt(512)
    for (int d = threadIdx.x; d < D_; d += blockDim.x) {
        int k = d >> 1;
        float ang = (float)s * expf((float)(2 * k) * (-logf(10000.0f) / (float)D_));
        float pe = (d & 1) ? cosf(ang) : sinf(ang);
        X[(size_t)bs * D_ + d] = emb[(size_t)t * D_ + d] * scale + pe;
    }
}

// ---------------------------------------------------------------------------
// Tiled fp32 GEMM: C[M,N] = A[M,K] @ B + bias (+ReLU)
// TRANSB=0: B stored [K,N]; TRANSB=1: B stored [N,K] (used for emb^T)
// BM=BN=64, BK=16, 256 threads, 4x4 microtile. M%64==0, N%64==0, K%16==0.
// ---------------------------------------------------------------------------
template <int TRANSB, int RELU>
__global__ void gemm_kernel(const float* __restrict__ A,
                            const float* __restrict__ Bm,
                            const float* __restrict__ bias,
                            float* __restrict__ C,
                            int M, int N, int K) {
    __shared__ float As[16][65];
    __shared__ float Bs[16][65];
    int tid = threadIdx.x;
    int tx = tid & 15, ty = tid >> 4;
    int m0 = blockIdx.y * 64, n0 = blockIdx.x * 64;
    float acc[4][4] = {};

    for (int k0 = 0; k0 < K; k0 += 16) {
        { // A tile: 64 rows x 16 k
            int m  = tid >> 2;
            int kk = (tid & 3) << 2;
            const float4 a = *(const float4*)(A + (size_t)(m0 + m) * K + k0 + kk);
            As[kk + 0][m] = a.x; As[kk + 1][m] = a.y;
            As[kk + 2][m] = a.z; As[kk + 3][m] = a.w;
        }
        if (TRANSB) { // B[N,K] -> Bs[kk][n]
            int n  = tid >> 2;
            int kk = (tid & 3) << 2;
            const float4 b = *(const float4*)(Bm + (size_t)(n0 + n) * K + k0 + kk);
            Bs[kk + 0][n] = b.x; Bs[kk + 1][n] = b.y;
            Bs[kk + 2][n] = b.z; Bs[kk + 3][n] = b.w;
        } else {      // B[K,N] -> Bs[kk][n]
            int kk = tid >> 4;
            int n  = (tid & 15) << 2;
            const float4 b = *(const float4*)(Bm + (size_t)(k0 + kk) * N + n0 + n);
            Bs[kk][n + 0] = b.x; Bs[kk][n + 1] = b.y;
            Bs[kk][n + 2] = b.z; Bs[kk][n + 3] = b.w;
        }
        __syncthreads();
        #pragma unroll
        for (int kk = 0; kk < 16; ++kk) {
            float a[4], b[4];
            #pragma unroll
            for (int i = 0; i < 4; ++i) a[i] = As[kk][ty * 4 + i];
            #pragma unroll
            for (int j = 0; j < 4; ++j) b[j] = Bs[kk][tx * 4 + j];
            #pragma unroll
            for (int i = 0; i < 4; ++i)
                #pragma unroll
                for (int j = 0; j < 4; ++j)
                    acc[i][j] += a[i] * b[j];
        }
        __syncthreads();
    }

    #pragma unroll
    for (int i = 0; i < 4; ++i) {
        int m = m0 + ty * 4 + i;
        #pragma unroll
        for (int j = 0; j < 4; ++j) {
            int n = n0 + tx * 4 + j;
            float v = acc[i][j] + bias[n];
            if (RELU) v = fmaxf(v, 0.0f);
            C[(size_t)m * N + n] = v;
        }
    }
}

// ---------------------------------------------------------------------------
// Sparse attention. Mask: causal & (local | strided | global).
// Allowed j for row i, duplicate-free decomposition:
//   set1 (local):   j in [jlo, i], jlo = max(0, i-255)           (c1 elems)
//   set2 (strided): j = i-128*t, t>=2, j>=16                     (c2 elems)
//   set3 (global):  j in [0, min(16, jlo))                       (c3 elems)
// One wave (64 threads) per (b, h, i). dh = 64 = wave size.
// ---------------------------------------------------------------------------
#define MAXJ 288
__global__ void attn_kernel(const float* __restrict__ Q,
                            const float* __restrict__ K,
                            const float* __restrict__ V,
                            float* __restrict__ O) {
    int i = blockIdx.x, h = blockIdx.y, b = blockIdx.z;
    int lane = threadIdx.x;
    __shared__ float qs[64];
    __shared__ int   jl[MAXJ];
    __shared__ float p[MAXJ];

    const size_t base = (size_t)b * S_ * D_ + (size_t)h * DH_;
    qs[lane] = Q[base + (size_t)i * D_ + lane];

    int jlo = max(0, i - 255);
    int c1 = i - jlo + 1;
    int c2 = (i >= 272) ? (((i - 16) >> 7) - 1) : 0;
    int c3 = min(16, jlo);
    int count = c1 + c2 + c3;

    for (int t = lane; t < count; t += 64) {
        int j;
        if (t < c1)            j = jlo + t;
        else if (t < c1 + c2)  j = i - ((t - c1 + 2) << 7);
        else                   j = t - c1 - c2;
        jl[t] = j;
    }
    __syncthreads();

    // scores
    float lmax = -1e30f;
    for (int t = lane; t < count; t += 64) {
        const float* kr = K + base + (size_t)jl[t] * D_;
        float s = 0.0f;
        #pragma unroll 16
        for (int d = 0; d < 64; ++d) s += qs[d] * kr[d];
        s *= 0.125f; // 1/sqrt(64)
        p[t] = s;
        lmax = fmaxf(lmax, s);
    }
    #pragma unroll
    for (int o = 32; o; o >>= 1) lmax = fmaxf(lmax, __shfl_xor(lmax, o));
    __syncthreads();

    float lsum = 0.0f;
    for (int t = lane; t < count; t += 64) {
        float e = expf(p[t] - lmax);
        p[t] = e;
        lsum += e;
    }
    #pragma unroll
    for (int o = 32; o; o >>= 1) lsum += __shfl_xor(lsum, o);
    float inv = 1.0f / lsum;
    __syncthreads();

    // o[d=lane] = sum_t p[t] * V[j_t, d]
    float od = 0.0f;
    for (int t = 0; t < count; ++t) {
        od += p[t] * V[base + (size_t)jl[t] * D_ + lane];
    }
    O[base + (size_t)i * D_ + lane] = od * inv;
}

// ---------------------------------------------------------------------------
// Fused residual add + LayerNorm (in-place on X): X = LN(X + T) * g + b
// One wave per row of 512.
// ---------------------------------------------------------------------------
__global__ void add_ln_kernel(float* __restrict__ X,
                              const float* __restrict__ T,
                              const float* __restrict__ g,
                              const float* __restrict__ bb) {
    size_t row = blockIdx.x;
    int lane = threadIdx.x;
    float v[8];
    float sum = 0.0f;
    #pragma unroll
    for (int q = 0; q < 8; ++q) {
        int d = lane + q * 64;
        v[q] = X[row * D_ + d] + T[row * D_ + d];
        sum += v[q];
    }
    #pragma unroll
    for (int o = 32; o; o >>= 1) sum += __shfl_xor(sum, o);
    float mean = sum * (1.0f / D_);
    float var = 0.0f;
    #pragma unroll
    for (int q = 0; q < 8; ++q) { float dd = v[q] - mean; var += dd * dd; }
    #pragma unroll
    for (int o = 32; o; o >>= 1) var += __shfl_xor(var, o);
    var *= (1.0f / D_);
    float r = rsqrtf(var + 1e-5f);
    #pragma unroll
    for (int q = 0; q < 8; ++q) {
        int d = lane + q * 64;
        X[row * D_ + d] = (v[q] - mean) * r * g[d] + bb[d];
    }
}

// ---------------------------------------------------------------------------
extern "C" void kernel_launch(void* const* d_in, const int* in_sizes, int n_in,
                              void* d_out, int out_size, void* d_ws, size_t ws_size,
                              hipStream_t stream) {
    const int*   tok   = (const int*)  d_in[0];
    const float* emb   = (const float*)d_in[1];
    const float* b_out = (const float*)d_in[2];
    const float* Wq    = (const float*)d_in[3];
    const float* bq    = (const float*)d_in[4];
    const float* Wk    = (const float*)d_in[5];
    const float* bk    = (const float*)d_in[6];
    const float* Wv    = (const float*)d_in[7];
    const float* bv    = (const float*)d_in[8];
    const float* Wo    = (const float*)d_in[9];
    const float* bo    = (const float*)d_in[10];
    const float* ln1g  = (const float*)d_in[11];
    const float* ln1b  = (const float*)d_in[12];
    const float* W1    = (const float*)d_in[13];
    const float* b1    = (const float*)d_in[14];
    const float* W2    = (const float*)d_in[15];
    const float* b2    = (const float*)d_in[16];
    const float* ln2g  = (const float*)d_in[17];
    const float* ln2b  = (const float*)d_in[18];
    float* out = (float*)d_out;

    float* ws = (float*)d_ws;
    float* X  = ws + 0 * XN;
    float* Q  = ws + 1 * XN;
    float* Kb = ws + 2 * XN;
    float* Vb = ws + 3 * XN;
    float* O  = ws + 4 * XN;
    float* T  = ws + 5 * XN;
    float* Hb = ws + 1 * XN;  // [NTOK, FF] = 4*XN, reuses Q/K/V/O after attention

    // x = emb[tok]*sqrt(D) + pos_enc
    embed_kernel<<<NTOK, 256, 0, stream>>>(tok, emb, X);

    dim3 g512(D_ / 64, NTOK / 64);     // N=512
    dim3 gff (FF_ / 64, NTOK / 64);    // N=2048
    dim3 gout(V_ / 64, NTOK / 64);     // N=256
    dim3 gattn(S_, H_, B_);

    for (int l = 0; l < L_; ++l) {
        const float* wq = Wq + (size_t)l * D_ * D_;
        const float* wk = Wk + (size_t)l * D_ * D_;
        const float* wv = Wv + (size_t)l * D_ * D_;
        const float* wo = Wo + (size_t)l * D_ * D_;
        const float* w1 = W1 + (size_t)l * D_ * FF_;
        const float* w2 = W2 + (size_t)l * FF_ * D_;

        gemm_kernel<0, 0><<<g512, 256, 0, stream>>>(X, wq, bq + l * D_, Q,  NTOK, D_, D_);
        gemm_kernel<0, 0><<<g512, 256, 0, stream>>>(X, wk, bk + l * D_, Kb, NTOK, D_, D_);
        gemm_kernel<0, 0><<<g512, 256, 0, stream>>>(X, wv, bv + l * D_, Vb, NTOK, D_, D_);

        attn_kernel<<<gattn, 64, 0, stream>>>(Q, Kb, Vb, O);

        gemm_kernel<0, 0><<<g512, 256, 0, stream>>>(O, wo, bo + l * D_, T, NTOK, D_, D_);
        add_ln_kernel<<<NTOK, 64, 0, stream>>>(X, T, ln1g + l * D_, ln1b + l * D_);

        gemm_kernel<0, 1><<<gff, 256, 0, stream>>>(X, w1, b1 + l * FF_, Hb, NTOK, FF_, D_);
        gemm_kernel<0, 0><<<g512, 256, 0, stream>>>(Hb, w2, b2 + l * D_, T, NTOK, D_, FF_);
        add_ln_kernel<<<NTOK, 64, 0, stream>>>(X, T, ln2g + l * D_, ln2b + l * D_);
    }

    // out = X @ emb^T + b_out   (emb stored [V, D] -> TRANSB)
    gemm_kernel<1, 0><<<gout, 256, 0, stream>>>(X, emb, b_out, out, NTOK, V_, D_);
}

// Round 2
// 2967.287 us; speedup vs baseline: 2.2432x; 2.2432x over previous
//
#include <hip/hip_runtime.h>
#include <hip/hip_bf16.h>
#include <math.h>

// Problem constants
#define B_  4
#define S_  2048
#define D_  512
#define H_  8
#define DH_ 64
#define FF_ 2048
#define L_  4
#define V_  256
#define NTOK (B_ * S_)          // 8192
#define XN  ((size_t)NTOK * D_) // 4,194,304 elems per [B,S,D] buffer

typedef __attribute__((ext_vector_type(8))) short bf16x8;
typedef __attribute__((ext_vector_type(4))) float f32x4;
typedef __attribute__((ext_vector_type(8))) unsigned short u16x8;

typedef const __attribute__((address_space(1))) unsigned int* gptr_u32;
typedef __attribute__((address_space(3))) unsigned int* lptr_u32;

__device__ __forceinline__ float bf2f(unsigned short u) {
    return __uint_as_float((unsigned)u << 16);
}

// ---------------------------------------------------------------------------
// Embedding + sinusoidal positional encoding -> X fp32 and Xb bf16
// ---------------------------------------------------------------------------
__global__ void embed_kernel(const int* __restrict__ tok,
                             const float* __restrict__ emb,
                             float* __restrict__ X,
                             __hip_bfloat16* __restrict__ Xb) {
    int bs = blockIdx.x;              // 0..NTOK-1
    int s = bs % S_;
    int t = tok[bs];
    const float scale = 22.62741699796952f; // sqrt(512)
    for (int d = threadIdx.x; d < D_; d += blockDim.x) {
        int k = d >> 1;
        float ang = (float)s * expf((float)(2 * k) * (-logf(10000.0f) / (float)D_));
        float pe = (d & 1) ? cosf(ang) : sinf(ang);
        float v = emb[(size_t)t * D_ + d] * scale + pe;
        X[(size_t)bs * D_ + d] = v;
        Xb[(size_t)bs * D_ + d] = __float2bfloat16(v);
    }
}

// ---------------------------------------------------------------------------
// Weight prep: fp32 [K,N] (per layer, blockIdx.z) -> bf16 [N,K]
// ---------------------------------------------------------------------------
__global__ void transpose_conv_kernel(const float* __restrict__ W,
                                      __hip_bfloat16* __restrict__ Wt,
                                      int K, int N) {
    const float* Wl = W + (size_t)blockIdx.z * K * N;
    __hip_bfloat16* Wtl = Wt + (size_t)blockIdx.z * K * N;
    __shared__ float t[32][33];
    int k0 = blockIdx.y * 32, n0 = blockIdx.x * 32;
    int tx = threadIdx.x & 31, ty = threadIdx.x >> 5; // 32 x 8
    #pragma unroll
    for (int q = 0; q < 4; ++q)
        t[ty + q * 8][tx] = Wl[(size_t)(k0 + ty + q * 8) * N + n0 + tx];
    __syncthreads();
    #pragma unroll
    for (int q = 0; q < 4; ++q)
        Wtl[(size_t)(n0 + ty + q * 8) * K + k0 + tx] =
            __float2bfloat16(t[tx][ty + q * 8]);
}

__global__ void conv_bf16_kernel(const float* __restrict__ in,
                                 __hip_bfloat16* __restrict__ out, int n) {
    int i = blockIdx.x * 256 + threadIdx.x;
    if (i < n) out[i] = __float2bfloat16(in[i]);
}

// ---------------------------------------------------------------------------
// bf16 MFMA GEMM (m97 structure): C[M,N] = A[M,K] @ Bt[N,K]^T + bias
// 128x128 tile, BK=32, 256 threads = 4 waves (2x2), each wave 64x64 out
// = 4x4 fragments of mfma_f32_16x16x32_bf16. global_load_lds width-16.
// M%128==0, N%128==0, K%32==0.
// ---------------------------------------------------------------------------
template <int RELU, int OUT_BF16>
__global__ __launch_bounds__(256)
void gemm_bf16_kernel(const __hip_bfloat16* __restrict__ A,
                      const __hip_bfloat16* __restrict__ Bt,
                      const float* __restrict__ bias,
                      float* __restrict__ Cf,
                      __hip_bfloat16* __restrict__ Cb,
                      int M, int N, int K) {
    __shared__ unsigned short As[128 * 32];
    __shared__ unsigned short Bs[128 * 32];
    int tid = threadIdx.x;
    int lane = tid & 63, wid = tid >> 6;
    int wm = (wid >> 1) * 64, wn = (wid & 1) * 64;
    int m0 = blockIdx.y * 128, n0 = blockIdx.x * 128;

    f32x4 acc[4][4] = {};

    for (int k0 = 0; k0 < K; k0 += 32) {
        #pragma unroll
        for (int q = 0; q < 2; ++q) {
            int idx = q * 256 + tid;           // 16B chunk index
            int r = idx >> 2, kc = (idx & 3) << 3;
            const __hip_bfloat16* src = A + (size_t)(m0 + r) * K + k0 + kc;
            __builtin_amdgcn_global_load_lds((gptr_u32)(const void*)src,
                                             (lptr_u32)(void*)&As[idx * 8],
                                             16, 0, 0);
        }
        #pragma unroll
        for (int q = 0; q < 2; ++q) {
            int idx = q * 256 + tid;
            int r = idx >> 2, kc = (idx & 3) << 3;
            const __hip_bfloat16* src = Bt + (size_t)(n0 + r) * K + k0 + kc;
            __builtin_amdgcn_global_load_lds((gptr_u32)(const void*)src,
                                             (lptr_u32)(void*)&Bs[idx * 8],
                                             16, 0, 0);
        }
        __syncthreads();

        bf16x8 af[4], bf[4];
        #pragma unroll
        for (int i = 0; i < 4; ++i) {
            int m = wm + i * 16 + (lane & 15);
            af[i] = *(const bf16x8*)&As[m * 32 + (lane >> 4) * 8];
            int n = wn + i * 16 + (lane & 15);
            bf[i] = *(const bf16x8*)&Bs[n * 32 + (lane >> 4) * 8];
        }
        #pragma unroll
        for (int i = 0; i < 4; ++i)
            #pragma unroll
            for (int j = 0; j < 4; ++j)
                acc[i][j] = __builtin_amdgcn_mfma_f32_16x16x32_bf16(
                    af[i], bf[j], acc[i][j], 0, 0, 0);
        __syncthreads();
    }

    // C/D layout: col = lane&15, row = (lane>>4)*4 + reg   [m89-verified]
    #pragma unroll
    for (int j = 0; j < 4; ++j) {
        int col = n0 + wn + j * 16 + (lane & 15);
        float bv = bias[col];
        #pragma unroll
        for (int i = 0; i < 4; ++i) {
            #pragma unroll
            for (int r = 0; r < 4; ++r) {
                int row = m0 + wm + i * 16 + (lane >> 4) * 4 + r;
                float v = acc[i][j][r] + bv;
                if (RELU) v = fmaxf(v, 0.0f);
                if (OUT_BF16) Cb[(size_t)row * N + col] = __float2bfloat16(v);
                else          Cf[(size_t)row * N + col] = v;
            }
        }
    }
}

// ---------------------------------------------------------------------------
// Sparse attention (bf16 in/out, fp32 math). Mask: causal & (local|strided|glob)
// Duplicate-free j decomposition per row i:
//   local:   j in [jlo, i], jlo = max(0, i-255)
//   strided: j = i-128*t, t>=2, j>=16
//   global:  j in [0, min(16, jlo))
// One wave per (b, h, i).
// ---------------------------------------------------------------------------
#define MAXJ 288
__global__ void attn_kernel(const __hip_bfloat16* __restrict__ Q,
                            const __hip_bfloat16* __restrict__ K,
                            const __hip_bfloat16* __restrict__ V,
                            __hip_bfloat16* __restrict__ O) {
    int i = blockIdx.x, h = blockIdx.y, b = blockIdx.z;
    int lane = threadIdx.x;
    __shared__ float qs[64];
    __shared__ int   jl[MAXJ];
    __shared__ float p[MAXJ];

    const size_t base = (size_t)b * S_ * D_ + (size_t)h * DH_;
    qs[lane] = __bfloat162float(Q[base + (size_t)i * D_ + lane]);

    int jlo = max(0, i - 255);
    int c1 = i - jlo + 1;
    int c2 = (i >= 272) ? (((i - 16) >> 7) - 1) : 0;
    int c3 = min(16, jlo);
    int count = c1 + c2 + c3;

    for (int t = lane; t < count; t += 64) {
        int j;
        if (t < c1)            j = jlo + t;
        else if (t < c1 + c2)  j = i - ((t - c1 + 2) << 7);
        else                   j = t - c1 - c2;
        jl[t] = j;
    }
    __syncthreads();

    float lmax = -1e30f;
    for (int t = lane; t < count; t += 64) {
        const unsigned short* kr = (const unsigned short*)(K + base + (size_t)jl[t] * D_);
        float s = 0.0f;
        #pragma unroll
        for (int c = 0; c < 8; ++c) {
            u16x8 kv = *(const u16x8*)(kr + c * 8);
            #pragma unroll
            for (int e = 0; e < 8; ++e) s += qs[c * 8 + e] * bf2f(kv[e]);
        }
        s *= 0.125f; // 1/sqrt(64)
        p[t] = s;
        lmax = fmaxf(lmax, s);
    }
    #pragma unroll
    for (int o = 32; o; o >>= 1) lmax = fmaxf(lmax, __shfl_xor(lmax, o));
    __syncthreads();

    float lsum = 0.0f;
    for (int t = lane; t < count; t += 64) {
        float e = expf(p[t] - lmax);
        p[t] = e;
        lsum += e;
    }
    #pragma unroll
    for (int o = 32; o; o >>= 1) lsum += __shfl_xor(lsum, o);
    float inv = 1.0f / lsum;
    __syncthreads();

    float od = 0.0f;
    for (int t = 0; t < count; ++t) {
        od += p[t] * __bfloat162float(V[base + (size_t)jl[t] * D_ + lane]);
    }
    O[base + (size_t)i * D_ + lane] = __float2bfloat16(od * inv);
}

// ---------------------------------------------------------------------------
// Fused residual add + LayerNorm: X = LN(X + T)*g + b  (X fp32, T bf16)
// also writes Xb (bf16 copy of new X). One wave per row.
// ---------------------------------------------------------------------------
__global__ void add_ln_kernel(float* __restrict__ X,
                              const __hip_bfloat16* __restrict__ T,
                              const float* __restrict__ g,
                              const float* __restrict__ bb,
                              __hip_bfloat16* __restrict__ Xb) {
    size_t row = blockIdx.x;
    int lane = threadIdx.x;
    float v[8];
    float sum = 0.0f;
    #pragma unroll
    for (int q = 0; q < 8; ++q) {
        int d = lane + q * 64;
        v[q] = X[row * D_ + d] + __bfloat162float(T[row * D_ + d]);
        sum += v[q];
    }
    #pragma unroll
    for (int o = 32; o; o >>= 1) sum += __shfl_xor(sum, o);
    float mean = sum * (1.0f / D_);
    float var = 0.0f;
    #pragma unroll
    for (int q = 0; q < 8; ++q) { float dd = v[q] - mean; var += dd * dd; }
    #pragma unroll
    for (int o = 32; o; o >>= 1) var += __shfl_xor(var, o);
    var *= (1.0f / D_);
    float r = rsqrtf(var + 1e-5f);
    #pragma unroll
    for (int q = 0; q < 8; ++q) {
        int d = lane + q * 64;
        float y = (v[q] - mean) * r * g[d] + bb[d];
        X[row * D_ + d] = y;
        Xb[row * D_ + d] = __float2bfloat16(y);
    }
}

// ---------------------------------------------------------------------------
extern "C" void kernel_launch(void* const* d_in, const int* in_sizes, int n_in,
                              void* d_out, int out_size, void* d_ws, size_t ws_size,
                              hipStream_t stream) {
    const int*   tok   = (const int*)  d_in[0];
    const float* emb   = (const float*)d_in[1];
    const float* b_out = (const float*)d_in[2];
    const float* Wq    = (const float*)d_in[3];
    const float* bq    = (const float*)d_in[4];
    const float* Wk    = (const float*)d_in[5];
    const float* bk    = (const float*)d_in[6];
    const float* Wv    = (const float*)d_in[7];
    const float* bv    = (const float*)d_in[8];
    const float* Wo    = (const float*)d_in[9];
    const float* bo    = (const float*)d_in[10];
    const float* ln1g  = (const float*)d_in[11];
    const float* ln1b  = (const float*)d_in[12];
    const float* W1    = (const float*)d_in[13];
    const float* b1    = (const float*)d_in[14];
    const float* W2    = (const float*)d_in[15];
    const float* b2    = (const float*)d_in[16];
    const float* ln2g  = (const float*)d_in[17];
    const float* ln2b  = (const float*)d_in[18];
    float* out = (float*)d_out;

    // ---- workspace layout (bump allocator, 256B aligned) ----
    char* w = (char*)d_ws;
    auto alloc = [&](size_t bytes) {
        char* p = w;
        w += (bytes + 255) & ~(size_t)255;
        return p;
    };
    float*          X   = (float*)         alloc(XN * 4);
    __hip_bfloat16* Xb  = (__hip_bfloat16*)alloc(XN * 2);
    __hip_bfloat16* Tb  = (__hip_bfloat16*)alloc(XN * 2);
    // union region: Qb/Kb/Vb/Ob (attention phase) == H (FFN phase), 32MB
    char* uni = alloc(XN * 2 * 4);
    __hip_bfloat16* Qb = (__hip_bfloat16*)uni;
    __hip_bfloat16* Kb = Qb + XN;
    __hip_bfloat16* Vb = Kb + XN;
    __hip_bfloat16* Ob = Vb + XN;
    __hip_bfloat16* Hb = (__hip_bfloat16*)uni;      // [NTOK, FF]
    __hip_bfloat16* Wqt  = (__hip_bfloat16*)alloc((size_t)L_ * D_ * D_ * 2);
    __hip_bfloat16* Wkt  = (__hip_bfloat16*)alloc((size_t)L_ * D_ * D_ * 2);
    __hip_bfloat16* Wvt  = (__hip_bfloat16*)alloc((size_t)L_ * D_ * D_ * 2);
    __hip_bfloat16* Wot  = (__hip_bfloat16*)alloc((size_t)L_ * D_ * D_ * 2);
    __hip_bfloat16* W1t  = (__hip_bfloat16*)alloc((size_t)L_ * D_ * FF_ * 2);
    __hip_bfloat16* W2t  = (__hip_bfloat16*)alloc((size_t)L_ * FF_ * D_ * 2);
    __hip_bfloat16* embb = (__hip_bfloat16*)alloc((size_t)V_ * D_ * 2);

    // ---- weight prep (runs every call; deterministic) ----
    {
        dim3 gdd(D_ / 32, D_ / 32, L_);
        transpose_conv_kernel<<<gdd, 256, 0, stream>>>(Wq, Wqt, D_, D_);
        transpose_conv_kernel<<<gdd, 256, 0, stream>>>(Wk, Wkt, D_, D_);
        transpose_conv_kernel<<<gdd, 256, 0, stream>>>(Wv, Wvt, D_, D_);
        transpose_conv_kernel<<<gdd, 256, 0, stream>>>(Wo, Wot, D_, D_);
        dim3 g1(FF_ / 32, D_ / 32, L_);
        transpose_conv_kernel<<<g1, 256, 0, stream>>>(W1, W1t, D_, FF_);
        dim3 g2(D_ / 32, FF_ / 32, L_);
        transpose_conv_kernel<<<g2, 256, 0, stream>>>(W2, W2t, FF_, D_);
        conv_bf16_kernel<<<(V_ * D_ + 255) / 256, 256, 0, stream>>>(emb, embb, V_ * D_);
    }

    embed_kernel<<<NTOK, 256, 0, stream>>>(tok, emb, X, Xb);

    dim3 blk(256);
    dim3 g512(D_ / 128, NTOK / 128);   // N=512:  4 x 64
    dim3 gff (FF_ / 128, NTOK / 128);  // N=2048: 16 x 64
    dim3 gout(V_ / 128, NTOK / 128);   // N=256:  2 x 64
    dim3 gattn(S_, H_, B_);

    for (int l = 0; l < L_; ++l) {
        const __hip_bfloat16* wqt = Wqt + (size_t)l * D_ * D_;
        const __hip_bfloat16* wkt = Wkt + (size_t)l * D_ * D_;
        const __hip_bfloat16* wvt = Wvt + (size_t)l * D_ * D_;
        const __hip_bfloat16* wot = Wot + (size_t)l * D_ * D_;
        const __hip_bfloat16* w1t = W1t + (size_t)l * D_ * FF_;
        const __hip_bfloat16* w2t = W2t + (size_t)l * FF_ * D_;

        gemm_bf16_kernel<0, 1><<<g512, blk, 0, stream>>>(Xb, wqt, bq + l * D_, nullptr, Qb, NTOK, D_, D_);
        gemm_bf16_kernel<0, 1><<<g512, blk, 0, stream>>>(Xb, wkt, bk + l * D_, nullptr, Kb, NTOK, D_, D_);
        gemm_bf16_kernel<0, 1><<<g512, blk, 0, stream>>>(Xb, wvt, bv + l * D_, nullptr, Vb, NTOK, D_, D_);

        attn_kernel<<<gattn, 64, 0, stream>>>(Qb, Kb, Vb, Ob);

        gemm_bf16_kernel<0, 1><<<g512, blk, 0, stream>>>(Ob, wot, bo + l * D_, nullptr, Tb, NTOK, D_, D_);
        add_ln_kernel<<<NTOK, 64, 0, stream>>>(X, Tb, ln1g + l * D_, ln1b + l * D_, Xb);

        gemm_bf16_kernel<1, 1><<<gff, blk, 0, stream>>>(Xb, w1t, b1 + l * FF_, nullptr, Hb, NTOK, FF_, D_);
        gemm_bf16_kernel<0, 1><<<g512, blk, 0, stream>>>(Hb, w2t, b2 + l * D_, nullptr, Tb, NTOK, D_, FF_);
        add_ln_kernel<<<NTOK, 64, 0, stream>>>(X, Tb, ln2g + l * D_, ln2b + l * D_, Xb);
    }

    // out = X @ emb^T + b_out  (emb [V,D] is already [N,K] for this GEMM)
    gemm_bf16_kernel<0, 0><<<gout, blk, 0, stream>>>(Xb, embb, b_out, out, nullptr, NTOK, V_, D_);
}

// Round 3
// 1001.833 us; speedup vs baseline: 6.6439x; 2.9619x over previous
//
#include <hip/hip_runtime.h>
#include <hip/hip_bf16.h>
#include <math.h>

// Problem constants
#define B_  4
#define S_  2048
#define D_  512
#define H_  8
#define DH_ 64
#define FF_ 2048
#define L_  4
#define V_  256
#define NTOK (B_ * S_)          // 8192
#define XN  ((size_t)NTOK * D_) // 4,194,304 elems per [B,S,D] buffer

typedef __attribute__((ext_vector_type(8))) short bf16x8;
typedef __attribute__((ext_vector_type(4))) float f32x4;
typedef __attribute__((ext_vector_type(8))) unsigned short u16x8;
typedef __attribute__((ext_vector_type(4))) unsigned short u16x4;

typedef const __attribute__((address_space(1))) unsigned int* gptr_u32;
typedef __attribute__((address_space(3))) unsigned int* lptr_u32;

__device__ __forceinline__ unsigned short f2bf_bits(float f) {
    __hip_bfloat16 t = __float2bfloat16(f);
    return *(unsigned short*)&t;
}

// ---------------------------------------------------------------------------
// Embedding + sinusoidal positional encoding -> X fp32 and Xb bf16
// ---------------------------------------------------------------------------
__global__ void embed_kernel(const int* __restrict__ tok,
                             const float* __restrict__ emb,
                             float* __restrict__ X,
                             __hip_bfloat16* __restrict__ Xb) {
    int bs = blockIdx.x;              // 0..NTOK-1
    int s = bs % S_;
    int t = tok[bs];
    const float scale = 22.62741699796952f; // sqrt(512)
    for (int d = threadIdx.x; d < D_; d += blockDim.x) {
        int k = d >> 1;
        float ang = (float)s * expf((float)(2 * k) * (-logf(10000.0f) / (float)D_));
        float pe = (d & 1) ? cosf(ang) : sinf(ang);
        float v = emb[(size_t)t * D_ + d] * scale + pe;
        X[(size_t)bs * D_ + d] = v;
        Xb[(size_t)bs * D_ + d] = __float2bfloat16(v);
    }
}

// ---------------------------------------------------------------------------
// Weight prep: fp32 [K,N] (per layer, blockIdx.z) -> bf16 [N,K]
// ---------------------------------------------------------------------------
__global__ void transpose_conv_kernel(const float* __restrict__ W,
                                      __hip_bfloat16* __restrict__ Wt,
                                      int K, int N) {
    const float* Wl = W + (size_t)blockIdx.z * K * N;
    __hip_bfloat16* Wtl = Wt + (size_t)blockIdx.z * K * N;
    __shared__ float t[32][33];
    int k0 = blockIdx.y * 32, n0 = blockIdx.x * 32;
    int tx = threadIdx.x & 31, ty = threadIdx.x >> 5; // 32 x 8
    #pragma unroll
    for (int q = 0; q < 4; ++q)
        t[ty + q * 8][tx] = Wl[(size_t)(k0 + ty + q * 8) * N + n0 + tx];
    __syncthreads();
    #pragma unroll
    for (int q = 0; q < 4; ++q)
        Wtl[(size_t)(n0 + ty + q * 8) * K + k0 + tx] =
            __float2bfloat16(t[tx][ty + q * 8]);
}

__global__ void conv_bf16_kernel(const float* __restrict__ in,
                                 __hip_bfloat16* __restrict__ out, int n) {
    int i = blockIdx.x * 256 + threadIdx.x;
    if (i < n) out[i] = __float2bfloat16(in[i]);
}

// ---------------------------------------------------------------------------
// bf16 MFMA GEMM (m97 structure): C[M,N] = A[M,K] @ Bt[N,K]^T + bias
// 128x128 tile, BK=32, 256 threads = 4 waves (2x2), each wave 64x64 out.
// OUT_MODE: 0 = fp32 [M,N], 1 = bf16 [M,N], 2 = bf16 V^T layout [B,H,64,S]
// ---------------------------------------------------------------------------
template <int RELU, int OUT_MODE>
__global__ __launch_bounds__(256)
void gemm_bf16_kernel(const __hip_bfloat16* __restrict__ A,
                      const __hip_bfloat16* __restrict__ Bt,
                      const float* __restrict__ bias,
                      float* __restrict__ Cf,
                      __hip_bfloat16* __restrict__ Cb,
                      int M, int N, int K) {
    __shared__ unsigned short As[128 * 32];
    __shared__ unsigned short Bs[128 * 32];
    int tid = threadIdx.x;
    int lane = tid & 63, wid = tid >> 6;
    int wm = (wid >> 1) * 64, wn = (wid & 1) * 64;
    int m0 = blockIdx.y * 128, n0 = blockIdx.x * 128;

    f32x4 acc[4][4] = {};

    for (int k0 = 0; k0 < K; k0 += 32) {
        #pragma unroll
        for (int q = 0; q < 2; ++q) {
            int idx = q * 256 + tid;           // 16B chunk index
            int r = idx >> 2, kc = (idx & 3) << 3;
            const __hip_bfloat16* src = A + (size_t)(m0 + r) * K + k0 + kc;
            __builtin_amdgcn_global_load_lds((gptr_u32)(const void*)src,
                                             (lptr_u32)(void*)&As[idx * 8],
                                             16, 0, 0);
        }
        #pragma unroll
        for (int q = 0; q < 2; ++q) {
            int idx = q * 256 + tid;
            int r = idx >> 2, kc = (idx & 3) << 3;
            const __hip_bfloat16* src = Bt + (size_t)(n0 + r) * K + k0 + kc;
            __builtin_amdgcn_global_load_lds((gptr_u32)(const void*)src,
                                             (lptr_u32)(void*)&Bs[idx * 8],
                                             16, 0, 0);
        }
        __syncthreads();

        bf16x8 af[4], bf[4];
        #pragma unroll
        for (int i = 0; i < 4; ++i) {
            int m = wm + i * 16 + (lane & 15);
            af[i] = *(const bf16x8*)&As[m * 32 + (lane >> 4) * 8];
            int n = wn + i * 16 + (lane & 15);
            bf[i] = *(const bf16x8*)&Bs[n * 32 + (lane >> 4) * 8];
        }
        #pragma unroll
        for (int i = 0; i < 4; ++i)
            #pragma unroll
            for (int j = 0; j < 4; ++j)
                acc[i][j] = __builtin_amdgcn_mfma_f32_16x16x32_bf16(
                    af[i], bf[j], acc[i][j], 0, 0, 0);
        __syncthreads();
    }

    // C/D layout: col = lane&15, row = (lane>>4)*4 + reg
    if (OUT_MODE == 2) {
        // V^T epilogue: out[(b*8+h)*64+dh][2048] = v, packed 4 rows (s) at a time
        #pragma unroll
        for (int j = 0; j < 4; ++j) {
            int col = n0 + wn + j * 16 + (lane & 15);
            float bv = bias[col];
            int hh = col >> 6, dh = col & 63;
            #pragma unroll
            for (int i = 0; i < 4; ++i) {
                int row0 = m0 + wm + i * 16 + (lane >> 4) * 4;
                int bb = row0 >> 11, s0 = row0 & 2047;
                u16x4 pk;
                #pragma unroll
                for (int r = 0; r < 4; ++r)
                    pk[r] = f2bf_bits(acc[i][j][r] + bv);
                *(u16x4*)(Cb + ((size_t)((bb * 8 + hh) * 64 + dh) * 2048 + s0)) = pk;
            }
        }
    } else {
        #pragma unroll
        for (int j = 0; j < 4; ++j) {
            int col = n0 + wn + j * 16 + (lane & 15);
            float bv = bias[col];
            #pragma unroll
            for (int i = 0; i < 4; ++i) {
                #pragma unroll
                for (int r = 0; r < 4; ++r) {
                    int row = m0 + wm + i * 16 + (lane >> 4) * 4 + r;
                    float v = acc[i][j][r] + bv;
                    if (RELU) v = fmaxf(v, 0.0f);
                    if (OUT_MODE == 1) Cb[(size_t)row * N + col] = __float2bfloat16(v);
                    else               Cf[(size_t)row * N + col] = v;
                }
            }
        }
    }
}

// ---------------------------------------------------------------------------
// MFMA block-sparse flash attention.
// Grid (S/64, H, B), 256 threads = 4 waves; wave w owns Q rows [i0+16w, i0+16w+16).
// Disjoint 64-wide j-tiles: {i0-64k, k=0..4} ∪ {i0-384-128m} ∪ {0}; exact
// reference mask applied per element -> no dedup needed.
// Swapped QK^T (lane owns one q-row), online softmax, P via per-wave LDS,
// PV from V^T tile. K/V^T tiles XOR-swizzled (rule 21: linear LDS dest +
// pre-swizzled global source + swizzled read).
// ---------------------------------------------------------------------------
__device__ __forceinline__ bf16x8 lds_frag(const unsigned short* base, int row, int chunk) {
    int byte = (row << 7) + (((chunk ^ (row & 7)) & 7) << 4);
    return *(const bf16x8*)((const char*)base + byte);
}

__global__ __launch_bounds__(256)
void attn_mfma_kernel(const __hip_bfloat16* __restrict__ Q,   // [NTOK][512]
                      const __hip_bfloat16* __restrict__ K,   // [NTOK][512]
                      const __hip_bfloat16* __restrict__ VT,  // [B*H*64][2048]
                      __hip_bfloat16* __restrict__ O) {       // [NTOK][512]
    __shared__ unsigned short Ks[2][64 * 64];
    __shared__ unsigned short Vs[2][64 * 64];
    __shared__ unsigned short Ps[4][16 * 64];

    int i0 = blockIdx.x * 64;
    int h = blockIdx.y, b = blockIdx.z;
    int tid = threadIdx.x, lane = tid & 63, wv = tid >> 6;
    int g = lane >> 4, il = lane & 15, g4 = g * 4;

    // tile list (computed, no arrays -> no scratch)
    int nloc = min(i0 >> 6, 4) + 1;
    int nstr = (i0 >= 384) ? ((i0 - 384) >> 7) + 1 : 0;
    int add0 = !((i0 <= 256) || (i0 >= 384 && (i0 & 127) == 0));
    int nt = nloc + nstr + add0;

    const size_t vt_off = (size_t)((b * 8 + h) * 64) * 2048;

    auto j0_of = [&](int t) {
        return (t < nloc) ? (i0 - 64 * t)
             : ((t < nloc + nstr) ? (i0 - 384 - 128 * (t - nloc)) : 0);
    };
    auto stage = [&](int buf, int j0) {
        #pragma unroll
        for (int q = 0; q < 2; ++q) {
            int idx = q * 256 + tid;
            int row = idx >> 3, c = idx & 7;
            int csw = c ^ (row & 7);
            const __hip_bfloat16* sk = K + (size_t)(b * 2048 + j0 + row) * 512 + h * 64 + csw * 8;
            __builtin_amdgcn_global_load_lds((gptr_u32)(const void*)sk,
                                             (lptr_u32)(void*)&Ks[buf][idx * 8], 16, 0, 0);
            const __hip_bfloat16* sv = VT + vt_off + (size_t)row * 2048 + j0 + csw * 8;
            __builtin_amdgcn_global_load_lds((gptr_u32)(const void*)sv,
                                             (lptr_u32)(void*)&Vs[buf][idx * 8], 16, 0, 0);
        }
    };

    // Q fragments (B-operand layout == A-row layout: lane owns q-row il)
    int iq = i0 + wv * 16 + il;
    bf16x8 qf[2];
    #pragma unroll
    for (int kh = 0; kh < 2; ++kh)
        qf[kh] = *(const bf16x8*)(Q + (size_t)(b * 2048 + iq) * 512 + h * 64 + kh * 32 + g * 8);

    unsigned short* myP = Ps[wv];
    f32x4 o[4] = {};
    float m = -1e30f, l = 0.0f;

    stage(0, j0_of(0));

    for (int t = 0; t < nt; ++t) {
        __syncthreads();
        int cur = t & 1;
        if (t + 1 < nt) stage(cur ^ 1, j0_of(t + 1));
        int j0 = j0_of(t);
        int mode = (j0 == i0) ? 1 : ((i0 - j0 <= 192) ? 0 : 2);

        // S^T[j][i] = K_tile @ Q^T : lane owns q-row il, j = 16*jn + g4 + r
        f32x4 s[4] = {};
        #pragma unroll
        for (int kh = 0; kh < 2; ++kh)
            #pragma unroll
            for (int jn = 0; jn < 4; ++jn) {
                bf16x8 a = lds_frag(Ks[cur], jn * 16 + il, kh * 4 + g);
                s[jn] = __builtin_amdgcn_mfma_f32_16x16x32_bf16(a, qf[kh], s[jn], 0, 0, 0);
            }

        // scale + mask + local max
        float mloc = -1e30f;
        if (mode == 0) {
            #pragma unroll
            for (int jn = 0; jn < 4; ++jn)
                #pragma unroll
                for (int r = 0; r < 4; ++r) {
                    float sv = s[jn][r] * 0.125f;
                    s[jn][r] = sv;
                    mloc = fmaxf(mloc, sv);
                }
        } else if (mode == 1) {
            #pragma unroll
            for (int jn = 0; jn < 4; ++jn)
                #pragma unroll
                for (int r = 0; r < 4; ++r) {
                    float sv = s[jn][r] * 0.125f;
                    int jg = j0 + jn * 16 + g4 + r;
                    sv = (iq - jg >= 0) ? sv : -1e30f;
                    s[jn][r] = sv;
                    mloc = fmaxf(mloc, sv);
                }
        } else {
            #pragma unroll
            for (int jn = 0; jn < 4; ++jn)
                #pragma unroll
                for (int r = 0; r < 4; ++r) {
                    float sv = s[jn][r] * 0.125f;
                    int jg = j0 + jn * 16 + g4 + r;
                    int dij = iq - jg;
                    bool ok = (dij >= 0) && ((dij < 256) || ((dij & 127) == 0) || (jg < 16));
                    sv = ok ? sv : -1e30f;
                    s[jn][r] = sv;
                    mloc = fmaxf(mloc, sv);
                }
        }
        mloc = fmaxf(mloc, __shfl_xor(mloc, 16));
        mloc = fmaxf(mloc, __shfl_xor(mloc, 32));
        float mnew = fmaxf(m, mloc);
        float alpha = expf(m - mnew);

        float lloc = 0.0f;
        #pragma unroll
        for (int jn = 0; jn < 4; ++jn)
            #pragma unroll
            for (int r = 0; r < 4; ++r) {
                float p = expf(s[jn][r] - mnew);
                s[jn][r] = p;
                lloc += p;
            }
        lloc += __shfl_xor(lloc, 16);
        lloc += __shfl_xor(lloc, 32);
        l = l * alpha + lloc;
        m = mnew;

        // rescale O (O rows are g4+r; alpha lives at lane == row)
        float ar[4];
        #pragma unroll
        for (int r = 0; r < 4; ++r) ar[r] = __shfl(alpha, g4 + r);
        #pragma unroll
        for (int dn = 0; dn < 4; ++dn)
            #pragma unroll
            for (int r = 0; r < 4; ++r) o[dn][r] *= ar[r];

        // P -> LDS (bf16, XOR-swizzled rows), then PV
        #pragma unroll
        for (int jn = 0; jn < 4; ++jn) {
            u16x4 pk;
            #pragma unroll
            for (int r = 0; r < 4; ++r) pk[r] = f2bf_bits(s[jn][r]);
            int byte = ((il << 7) + (jn << 5) + (g << 3)) ^ ((il & 7) << 4);
            *(u16x4*)((char*)myP + byte) = pk;
        }
        #pragma unroll
        for (int kh = 0; kh < 2; ++kh) {
            bf16x8 pa = lds_frag(myP, il, kh * 4 + g);
            #pragma unroll
            for (int dn = 0; dn < 4; ++dn) {
                bf16x8 bv = lds_frag(Vs[cur], dn * 16 + il, kh * 4 + g);
                o[dn] = __builtin_amdgcn_mfma_f32_16x16x32_bf16(pa, bv, o[dn], 0, 0, 0);
            }
        }
    }

    // epilogue: O /= l, write bf16
    float li[4];
    #pragma unroll
    for (int r = 0; r < 4; ++r) li[r] = 1.0f / __shfl(l, g4 + r);
    #pragma unroll
    for (int dn = 0; dn < 4; ++dn)
        #pragma unroll
        for (int r = 0; r < 4; ++r) {
            int row = i0 + wv * 16 + g4 + r;
            O[(size_t)(b * 2048 + row) * 512 + h * 64 + dn * 16 + il] =
                __float2bfloat16(o[dn][r] * li[r]);
        }
}

// ---------------------------------------------------------------------------
// Fused residual add + LayerNorm: X = LN(X + T)*g + b  (X fp32, T bf16)
// ---------------------------------------------------------------------------
__global__ void add_ln_kernel(float* __restrict__ X,
                              const __hip_bfloat16* __restrict__ T,
                              const float* __restrict__ g,
                              const float* __restrict__ bb,
                              __hip_bfloat16* __restrict__ Xb) {
    size_t row = blockIdx.x;
    int lane = threadIdx.x;
    float v[8];
    float sum = 0.0f;
    #pragma unroll
    for (int q = 0; q < 8; ++q) {
        int d = lane + q * 64;
        v[q] = X[row * D_ + d] + __bfloat162float(T[row * D_ + d]);
        sum += v[q];
    }
    #pragma unroll
    for (int o = 32; o; o >>= 1) sum += __shfl_xor(sum, o);
    float mean = sum * (1.0f / D_);
    float var = 0.0f;
    #pragma unroll
    for (int q = 0; q < 8; ++q) { float dd = v[q] - mean; var += dd * dd; }
    #pragma unroll
    for (int o = 32; o; o >>= 1) var += __shfl_xor(var, o);
    var *= (1.0f / D_);
    float r = rsqrtf(var + 1e-5f);
    #pragma unroll
    for (int q = 0; q < 8; ++q) {
        int d = lane + q * 64;
        float y = (v[q] - mean) * r * g[d] + bb[d];
        X[row * D_ + d] = y;
        Xb[row * D_ + d] = __float2bfloat16(y);
    }
}

// ---------------------------------------------------------------------------
extern "C" void kernel_launch(void* const* d_in, const int* in_sizes, int n_in,
                              void* d_out, int out_size, void* d_ws, size_t ws_size,
                              hipStream_t stream) {
    const int*   tok   = (const int*)  d_in[0];
    const float* emb   = (const float*)d_in[1];
    const float* b_out = (const float*)d_in[2];
    const float* Wq    = (const float*)d_in[3];
    const float* bq    = (const float*)d_in[4];
    const float* Wk    = (const float*)d_in[5];
    const float* bk    = (const float*)d_in[6];
    const float* Wv    = (const float*)d_in[7];
    const float* bv    = (const float*)d_in[8];
    const float* Wo    = (const float*)d_in[9];
    const float* bo    = (const float*)d_in[10];
    const float* ln1g  = (const float*)d_in[11];
    const float* ln1b  = (const float*)d_in[12];
    const float* W1    = (const float*)d_in[13];
    const float* b1    = (const float*)d_in[14];
    const float* W2    = (const float*)d_in[15];
    const float* b2    = (const float*)d_in[16];
    const float* ln2g  = (const float*)d_in[17];
    const float* ln2b  = (const float*)d_in[18];
    float* out = (float*)d_out;

    // ---- workspace layout ----
    char* w = (char*)d_ws;
    auto alloc = [&](size_t bytes) {
        char* p = w;
        w += (bytes + 255) & ~(size_t)255;
        return p;
    };
    float*          X   = (float*)         alloc(XN * 4);
    __hip_bfloat16* Xb  = (__hip_bfloat16*)alloc(XN * 2);
    __hip_bfloat16* Tb  = (__hip_bfloat16*)alloc(XN * 2);
    char* uni = alloc(XN * 2 * 4);
    __hip_bfloat16* Qb  = (__hip_bfloat16*)uni;
    __hip_bfloat16* Kb  = Qb + XN;
    __hip_bfloat16* VTb = Kb + XN;   // [B,H,64,S]
    __hip_bfloat16* Ob  = VTb + XN;
    __hip_bfloat16* Hb  = (__hip_bfloat16*)uni;      // [NTOK, FF]
    __hip_bfloat16* Wqt  = (__hip_bfloat16*)alloc((size_t)L_ * D_ * D_ * 2);
    __hip_bfloat16* Wkt  = (__hip_bfloat16*)alloc((size_t)L_ * D_ * D_ * 2);
    __hip_bfloat16* Wvt  = (__hip_bfloat16*)alloc((size_t)L_ * D_ * D_ * 2);
    __hip_bfloat16* Wot  = (__hip_bfloat16*)alloc((size_t)L_ * D_ * D_ * 2);
    __hip_bfloat16* W1t  = (__hip_bfloat16*)alloc((size_t)L_ * D_ * FF_ * 2);
    __hip_bfloat16* W2t  = (__hip_bfloat16*)alloc((size_t)L_ * FF_ * D_ * 2);
    __hip_bfloat16* embb = (__hip_bfloat16*)alloc((size_t)V_ * D_ * 2);

    // ---- weight prep ----
    {
        dim3 gdd(D_ / 32, D_ / 32, L_);
        transpose_conv_kernel<<<gdd, 256, 0, stream>>>(Wq, Wqt, D_, D_);
        transpose_conv_kernel<<<gdd, 256, 0, stream>>>(Wk, Wkt, D_, D_);
        transpose_conv_kernel<<<gdd, 256, 0, stream>>>(Wv, Wvt, D_, D_);
        transpose_conv_kernel<<<gdd, 256, 0, stream>>>(Wo, Wot, D_, D_);
        dim3 g1(FF_ / 32, D_ / 32, L_);
        transpose_conv_kernel<<<g1, 256, 0, stream>>>(W1, W1t, D_, FF_);
        dim3 g2(D_ / 32, FF_ / 32, L_);
        transpose_conv_kernel<<<g2, 256, 0, stream>>>(W2, W2t, FF_, D_);
        conv_bf16_kernel<<<(V_ * D_ + 255) / 256, 256, 0, stream>>>(emb, embb, V_ * D_);
    }

    embed_kernel<<<NTOK, 256, 0, stream>>>(tok, emb, X, Xb);

    dim3 blk(256);
    dim3 g512(D_ / 128, NTOK / 128);
    dim3 gff (FF_ / 128, NTOK / 128);
    dim3 gout(V_ / 128, NTOK / 128);
    dim3 gattn(S_ / 64, H_, B_);

    for (int l = 0; l < L_; ++l) {
        const __hip_bfloat16* wqt = Wqt + (size_t)l * D_ * D_;
        const __hip_bfloat16* wkt = Wkt + (size_t)l * D_ * D_;
        const __hip_bfloat16* wvt = Wvt + (size_t)l * D_ * D_;
        const __hip_bfloat16* wot = Wot + (size_t)l * D_ * D_;
        const __hip_bfloat16* w1t = W1t + (size_t)l * D_ * FF_;
        const __hip_bfloat16* w2t = W2t + (size_t)l * FF_ * D_;

        gemm_bf16_kernel<0, 1><<<g512, blk, 0, stream>>>(Xb, wqt, bq + l * D_, nullptr, Qb, NTOK, D_, D_);
        gemm_bf16_kernel<0, 1><<<g512, blk, 0, stream>>>(Xb, wkt, bk + l * D_, nullptr, Kb, NTOK, D_, D_);
        gemm_bf16_kernel<0, 2><<<g512, blk, 0, stream>>>(Xb, wvt, bv + l * D_, nullptr, VTb, NTOK, D_, D_);

        attn_mfma_kernel<<<gattn, blk, 0, stream>>>(Qb, Kb, VTb, Ob);

        gemm_bf16_kernel<0, 1><<<g512, blk, 0, stream>>>(Ob, wot, bo + l * D_, nullptr, Tb, NTOK, D_, D_);
        add_ln_kernel<<<NTOK, 64, 0, stream>>>(X, Tb, ln1g + l * D_, ln1b + l * D_, Xb);

        gemm_bf16_kernel<1, 1><<<gff, blk, 0, stream>>>(Xb, w1t, b1 + l * FF_, nullptr, Hb, NTOK, FF_, D_);
        gemm_bf16_kernel<0, 1><<<g512, blk, 0, stream>>>(Hb, w2t, b2 + l * D_, nullptr, Tb, NTOK, D_, FF_);
        add_ln_kernel<<<NTOK, 64, 0, stream>>>(X, Tb, ln2g + l * D_, ln2b + l * D_, Xb);
    }

    gemm_bf16_kernel<0, 0><<<gout, blk, 0, stream>>>(Xb, embb, b_out, out, nullptr, NTOK, V_, D_);
}

// Round 4
// 850.368 us; speedup vs baseline: 7.8273x; 1.1781x over previous
//
#include <hip/hip_runtime.h>
#include <hip/hip_bf16.h>
#include <math.h>

// Problem constants
#define B_  4
#define S_  2048
#define D_  512
#define H_  8
#define DH_ 64
#define FF_ 2048
#define L_  4
#define V_  256
#define NTOK (B_ * S_)          // 8192
#define XN  ((size_t)NTOK * D_) // 4,194,304 elems per [B,S,D] buffer

typedef __attribute__((ext_vector_type(8))) short bf16x8;
typedef __attribute__((ext_vector_type(4))) float f32x4;
typedef __attribute__((ext_vector_type(8))) unsigned short u16x8;
typedef __attribute__((ext_vector_type(4))) unsigned short u16x4;

typedef const __attribute__((address_space(1))) unsigned int* gptr_u32;
typedef __attribute__((address_space(3))) unsigned int* lptr_u32;

__device__ __forceinline__ float bf2f(unsigned short u) {
    return __uint_as_float((unsigned)u << 16);
}
__device__ __forceinline__ unsigned short f2bf_bits(float f) {
    __hip_bfloat16 t = __float2bfloat16(f);
    return *(unsigned short*)&t;
}

// ---------------------------------------------------------------------------
// Embedding + sinusoidal positional encoding -> X fp32 and Xb bf16
// ---------------------------------------------------------------------------
__global__ void embed_kernel(const int* __restrict__ tok,
                             const float* __restrict__ emb,
                             float* __restrict__ X,
                             __hip_bfloat16* __restrict__ Xb) {
    int bs = blockIdx.x;
    int s = bs % S_;
    int t = tok[bs];
    const float scale = 22.62741699796952f; // sqrt(512)
    for (int d = threadIdx.x; d < D_; d += blockDim.x) {
        int k = d >> 1;
        float ang = (float)s * expf((float)(2 * k) * (-logf(10000.0f) / (float)D_));
        float pe = (d & 1) ? cosf(ang) : sinf(ang);
        float v = emb[(size_t)t * D_ + d] * scale + pe;
        X[(size_t)bs * D_ + d] = v;
        Xb[(size_t)bs * D_ + d] = __float2bfloat16(v);
    }
}

// ---------------------------------------------------------------------------
// Weight prep
// ---------------------------------------------------------------------------
__global__ void transpose_conv_kernel(const float* __restrict__ W,
                                      __hip_bfloat16* __restrict__ Wt,
                                      int K, int N) {
    const float* Wl = W + (size_t)blockIdx.z * K * N;
    __hip_bfloat16* Wtl = Wt + (size_t)blockIdx.z * K * N;
    __shared__ float t[32][33];
    int k0 = blockIdx.y * 32, n0 = blockIdx.x * 32;
    int tx = threadIdx.x & 31, ty = threadIdx.x >> 5;
    #pragma unroll
    for (int q = 0; q < 4; ++q)
        t[ty + q * 8][tx] = Wl[(size_t)(k0 + ty + q * 8) * N + n0 + tx];
    __syncthreads();
    #pragma unroll
    for (int q = 0; q < 4; ++q)
        Wtl[(size_t)(n0 + ty + q * 8) * K + k0 + tx] =
            __float2bfloat16(t[tx][ty + q * 8]);
}

// QKV fused: dst[l][1536][512], rows 0-511 Wq^T, 512-1023 Wk^T, 1024-1535 Wv^T
__global__ void transpose_qkv_kernel(const float* __restrict__ Wq,
                                     const float* __restrict__ Wk,
                                     const float* __restrict__ Wv,
                                     __hip_bfloat16* __restrict__ dst) {
    int z = blockIdx.z, l = z / 3, which = z % 3;
    const float* src = (which == 0 ? Wq : which == 1 ? Wk : Wv) + (size_t)l * D_ * D_;
    __hip_bfloat16* d = dst + (size_t)l * 1536 * D_ + (size_t)which * D_ * D_;
    __shared__ float t[32][33];
    int k0 = blockIdx.y * 32, n0 = blockIdx.x * 32;
    int tx = threadIdx.x & 31, ty = threadIdx.x >> 5;
    #pragma unroll
    for (int q = 0; q < 4; ++q)
        t[ty + q * 8][tx] = src[(size_t)(k0 + ty + q * 8) * D_ + n0 + tx];
    __syncthreads();
    #pragma unroll
    for (int q = 0; q < 4; ++q)
        d[(size_t)(n0 + ty + q * 8) * D_ + k0 + tx] =
            __float2bfloat16(t[tx][ty + q * 8]);
}

__global__ void conv_bf16_kernel(const float* __restrict__ in,
                                 __hip_bfloat16* __restrict__ out, int n) {
    int i = blockIdx.x * 256 + threadIdx.x;
    if (i < n) out[i] = __float2bfloat16(in[i]);
}

// ---------------------------------------------------------------------------
// bf16 MFMA GEMM (m97 structure): C[M,N] = A[M,K] @ Bt[N,K]^T + bias
// OUT_MODE: 0 = fp32 [M,N]; 1 = bf16 [M,N]; 4 = QKV fused (N=1536):
//   seg 0 -> Cb0 (Q), seg 1 -> Cb1 (K), seg 2 -> Cb2 (V row) + CbT (V^T [B,H,64,S])
// ---------------------------------------------------------------------------
template <int RELU, int OUT_MODE>
__global__ __launch_bounds__(256)
void gemm_bf16_kernel(const __hip_bfloat16* __restrict__ A,
                      const __hip_bfloat16* __restrict__ Bt,
                      const float* __restrict__ bias0,
                      const float* __restrict__ bias1,
                      const float* __restrict__ bias2,
                      float* __restrict__ Cf,
                      __hip_bfloat16* __restrict__ Cb0,
                      __hip_bfloat16* __restrict__ Cb1,
                      __hip_bfloat16* __restrict__ Cb2,
                      __hip_bfloat16* __restrict__ CbT,
                      int M, int N, int K) {
    __shared__ unsigned short As[128 * 32];
    __shared__ unsigned short Bs[128 * 32];
    int tid = threadIdx.x;
    int lane = tid & 63, wid = tid >> 6;
    int wm = (wid >> 1) * 64, wn = (wid & 1) * 64;
    int m0 = blockIdx.y * 128, n0 = blockIdx.x * 128;

    f32x4 acc[4][4] = {};

    for (int k0 = 0; k0 < K; k0 += 32) {
        #pragma unroll
        for (int q = 0; q < 2; ++q) {
            int idx = q * 256 + tid;
            int r = idx >> 2, kc = (idx & 3) << 3;
            const __hip_bfloat16* src = A + (size_t)(m0 + r) * K + k0 + kc;
            __builtin_amdgcn_global_load_lds((gptr_u32)(const void*)src,
                                             (lptr_u32)(void*)&As[idx * 8], 16, 0, 0);
        }
        #pragma unroll
        for (int q = 0; q < 2; ++q) {
            int idx = q * 256 + tid;
            int r = idx >> 2, kc = (idx & 3) << 3;
            const __hip_bfloat16* src = Bt + (size_t)(n0 + r) * K + k0 + kc;
            __builtin_amdgcn_global_load_lds((gptr_u32)(const void*)src,
                                             (lptr_u32)(void*)&Bs[idx * 8], 16, 0, 0);
        }
        __syncthreads();

        bf16x8 af[4], bf[4];
        #pragma unroll
        for (int i = 0; i < 4; ++i) {
            int m = wm + i * 16 + (lane & 15);
            af[i] = *(const bf16x8*)&As[m * 32 + (lane >> 4) * 8];
            int n = wn + i * 16 + (lane & 15);
            bf[i] = *(const bf16x8*)&Bs[n * 32 + (lane >> 4) * 8];
        }
        #pragma unroll
        for (int i = 0; i < 4; ++i)
            #pragma unroll
            for (int j = 0; j < 4; ++j)
                acc[i][j] = __builtin_amdgcn_mfma_f32_16x16x32_bf16(
                    af[i], bf[j], acc[i][j], 0, 0, 0);
        __syncthreads();
    }

    // C/D layout: col = lane&15, row = (lane>>4)*4 + reg
    if (OUT_MODE == 4) {
        int seg = n0 >> 9;                       // block-uniform
        const float* bias = seg == 0 ? bias0 : seg == 1 ? bias1 : bias2;
        __hip_bfloat16* Crow = seg == 0 ? Cb0 : seg == 1 ? Cb1 : Cb2;
        int nseg = n0 & 511;
        #pragma unroll
        for (int j = 0; j < 4; ++j) {
            int coll = nseg + wn + j * 16 + (lane & 15);   // 0..511 within segment
            float bv = bias[coll];
            #pragma unroll
            for (int i = 0; i < 4; ++i) {
                int row0 = m0 + wm + i * 16 + (lane >> 4) * 4;
                if (seg < 2) {
                    #pragma unroll
                    for (int r = 0; r < 4; ++r)
                        Crow[(size_t)(row0 + r) * 512 + coll] =
                            __float2bfloat16(acc[i][j][r] + bv);
                } else {
                    u16x4 pk;
                    #pragma unroll
                    for (int r = 0; r < 4; ++r) {
                        float v = acc[i][j][r] + bv;
                        Crow[(size_t)(row0 + r) * 512 + coll] = __float2bfloat16(v);
                        pk[r] = f2bf_bits(v);
                    }
                    int hh = coll >> 6, dh = coll & 63;
                    int bb = row0 >> 11, s0 = row0 & 2047;
                    *(u16x4*)(CbT + ((size_t)((bb * 8 + hh) * 64 + dh) * 2048 + s0)) = pk;
                }
            }
        }
    } else {
        #pragma unroll
        for (int j = 0; j < 4; ++j) {
            int col = n0 + wn + j * 16 + (lane & 15);
            float bv = bias0[col];
            #pragma unroll
            for (int i = 0; i < 4; ++i) {
                #pragma unroll
                for (int r = 0; r < 4; ++r) {
                    int row = m0 + wm + i * 16 + (lane >> 4) * 4 + r;
                    float v = acc[i][j][r] + bv;
                    if (RELU) v = fmaxf(v, 0.0f);
                    if (OUT_MODE == 1) Cb0[(size_t)row * N + col] = __float2bfloat16(v);
                    else               Cf[(size_t)row * N + col] = v;
                }
            }
        }
    }
}

// ---------------------------------------------------------------------------
// MFMA block-sparse flash attention, v2.
// MFMA tiles: local {i0-64k, k=0..min(i0/64,4)} + (i0>256 ? tile0 w/ j<16 mask : none).
// Strided keys j = iq-128m (m>=3, j>=16) via per-lane diagonal dot phase:
//   lanes (il, g=0..3) share q-row iq = i0+16wv+il; lane g covers dims
//   {g*8..g*8+7, 32+g*8..+7}; dot reduced over g by shfl; PV accumulated into
//   per-lane os[16], merged with the MFMA O-fragment via LDS at epilogue.
// Softmax in log2 domain (exp2), rescale skipped when max unchanged.
// ---------------------------------------------------------------------------
__device__ __forceinline__ bf16x8 lds_frag(const unsigned short* base, int row, int chunk) {
    int byte = (row << 7) + (((chunk ^ (row & 7)) & 7) << 4);
    return *(const bf16x8*)((const char*)base + byte);
}

__global__ __launch_bounds__(256)
void attn_mfma_kernel(const __hip_bfloat16* __restrict__ Q,   // [NTOK][512]
                      const __hip_bfloat16* __restrict__ K,   // [NTOK][512]
                      const __hip_bfloat16* __restrict__ V,   // [NTOK][512]
                      const __hip_bfloat16* __restrict__ VT,  // [B*H*64][2048]
                      __hip_bfloat16* __restrict__ O) {       // [NTOK][512]
    __shared__ unsigned short Ks[2][64 * 64];
    __shared__ unsigned short Vs[2][64 * 64];
    __shared__ unsigned short Ps[4][16 * 64];

    int i0 = blockIdx.x * 64;
    int h = blockIdx.y, b = blockIdx.z;
    int tid = threadIdx.x, lane = tid & 63, wv = tid >> 6;
    int g = lane >> 4, il = lane & 15, g4 = g * 4;

    int nloc = min(i0 >> 6, 4) + 1;
    int add0 = (i0 > 256);
    int nt = nloc + add0;

    const size_t vt_off = (size_t)((b * 8 + h) * 64) * 2048;
    auto j0_of = [&](int t) { return (t < nloc) ? (i0 - 64 * t) : 0; };

    auto stage = [&](int buf, int j0) {
        #pragma unroll
        for (int q = 0; q < 2; ++q) {
            int idx = q * 256 + tid;
            int row = idx >> 3, c = idx & 7;
            int csw = c ^ (row & 7);
            const __hip_bfloat16* sk = K + (size_t)(b * 2048 + j0 + row) * 512 + h * 64 + csw * 8;
            __builtin_amdgcn_global_load_lds((gptr_u32)(const void*)sk,
                                             (lptr_u32)(void*)&Ks[buf][idx * 8], 16, 0, 0);
            const __hip_bfloat16* sv = VT + vt_off + (size_t)row * 2048 + j0 + csw * 8;
            __builtin_amdgcn_global_load_lds((gptr_u32)(const void*)sv,
                                             (lptr_u32)(void*)&Vs[buf][idx * 8], 16, 0, 0);
        }
    };

    int iq = i0 + wv * 16 + il;
    bf16x8 qf[2];
    #pragma unroll
    for (int kh = 0; kh < 2; ++kh)
        qf[kh] = *(const bf16x8*)(Q + (size_t)(b * 2048 + iq) * 512 + h * 64 + kh * 32 + g * 8);

    stage(0, j0_of(0));   // overlap first tile load with scalar phase

    float qfl[16];
    #pragma unroll
    for (int kh = 0; kh < 2; ++kh)
        #pragma unroll
        for (int e = 0; e < 8; ++e)
            qfl[kh * 8 + e] = bf2f(((u16x8)qf[kh])[e]);

    unsigned short* myP = Ps[wv];
    f32x4 o[4] = {};
    float os[16] = {};
    float m = -1e30f, l = 0.0f;
    const float CSC = 0.18033688011112042f; // 0.125 * log2(e)

    // ---- scalar strided phase ----
    const unsigned short* Kbase = (const unsigned short*)(K + (size_t)b * 2048 * 512 + h * 64);
    const unsigned short* Vbase = (const unsigned short*)(V + (size_t)b * 2048 * 512 + h * 64);
    for (int j = iq - 384; j >= 16; j -= 128) {
        const unsigned short* kr = Kbase + (size_t)j * 512;
        u16x8 k0 = *(const u16x8*)(kr + g * 8);
        u16x8 k1 = *(const u16x8*)(kr + 32 + g * 8);
        float dot = 0.0f;
        #pragma unroll
        for (int e = 0; e < 8; ++e)
            dot += qfl[e] * bf2f(k0[e]) + qfl[8 + e] * bf2f(k1[e]);
        dot += __shfl_xor(dot, 16);
        dot += __shfl_xor(dot, 32);
        float s2 = dot * CSC;
        float mn = fmaxf(m, s2);
        float al = exp2f(m - mn);
        float p = exp2f(s2 - mn);
        l = l * al + p;
        m = mn;
        const unsigned short* vr = Vbase + (size_t)j * 512;
        u16x8 v0 = *(const u16x8*)(vr + g * 8);
        u16x8 v1 = *(const u16x8*)(vr + 32 + g * 8);
        #pragma unroll
        for (int e = 0; e < 8; ++e) {
            os[e]     = os[e]     * al + p * bf2f(v0[e]);
            os[8 + e] = os[8 + e] * al + p * bf2f(v1[e]);
        }
    }

    // ---- MFMA tile phase ----
    for (int t = 0; t < nt; ++t) {
        __syncthreads();
        int cur = t & 1;
        if (t + 1 < nt) stage(cur ^ 1, j0_of(t + 1));
        int j0 = j0_of(t);

        f32x4 s[4] = {};
        #pragma unroll
        for (int kh = 0; kh < 2; ++kh)
            #pragma unroll
            for (int jn = 0; jn < 4; ++jn) {
                bf16x8 a = lds_frag(Ks[cur], jn * 16 + il, kh * 4 + g);
                s[jn] = __builtin_amdgcn_mfma_f32_16x16x32_bf16(a, qf[kh], s[jn], 0, 0, 0);
            }

        float mloc = -1e30f;
        if (t >= nloc) {           // global tile: j<16 only
            #pragma unroll
            for (int jn = 0; jn < 4; ++jn)
                #pragma unroll
                for (int r = 0; r < 4; ++r) {
                    int jg = jn * 16 + g4 + r;
                    float sv = (jg < 16) ? s[jn][r] * CSC : -1e30f;
                    s[jn][r] = sv;
                    mloc = fmaxf(mloc, sv);
                }
        } else if (t == 0) {       // diagonal: causal
            #pragma unroll
            for (int jn = 0; jn < 4; ++jn)
                #pragma unroll
                for (int r = 0; r < 4; ++r) {
                    int jg = j0 + jn * 16 + g4 + r;
                    float sv = (iq >= jg) ? s[jn][r] * CSC : -1e30f;
                    s[jn][r] = sv;
                    mloc = fmaxf(mloc, sv);
                }
        } else if (t == 4) {       // window edge: local | strided | global
            #pragma unroll
            for (int jn = 0; jn < 4; ++jn)
                #pragma unroll
                for (int r = 0; r < 4; ++r) {
                    int jg = j0 + jn * 16 + g4 + r;
                    int dij = iq - jg;
                    bool ok = (dij < 256) || ((dij & 127) == 0) || (jg < 16);
                    float sv = ok ? s[jn][r] * CSC : -1e30f;
                    s[jn][r] = sv;
                    mloc = fmaxf(mloc, sv);
                }
        } else {                   // fully inside window
            #pragma unroll
            for (int jn = 0; jn < 4; ++jn)
                #pragma unroll
                for (int r = 0; r < 4; ++r) {
                    float sv = s[jn][r] * CSC;
                    s[jn][r] = sv;
                    mloc = fmaxf(mloc, sv);
                }
        }
        mloc = fmaxf(mloc, __shfl_xor(mloc, 16));
        mloc = fmaxf(mloc, __shfl_xor(mloc, 32));
        float mn = fmaxf(m, mloc);
        float al = exp2f(m - mn);

        float lloc = 0.0f;
        #pragma unroll
        for (int jn = 0; jn < 4; ++jn)
            #pragma unroll
            for (int r = 0; r < 4; ++r) {
                float p = exp2f(s[jn][r] - mn);
                s[jn][r] = p;
                lloc += p;
            }
        lloc += __shfl_xor(lloc, 16);
        lloc += __shfl_xor(lloc, 32);
        l = l * al + lloc;
        m = mn;

        if (!__all(al == 1.0f)) {
            float ar[4];
            #pragma unroll
            for (int r = 0; r < 4; ++r) ar[r] = __shfl(al, g4 + r);
            #pragma unroll
            for (int dn = 0; dn < 4; ++dn)
                #pragma unroll
                for (int r = 0; r < 4; ++r) o[dn][r] *= ar[r];
            #pragma unroll
            for (int e = 0; e < 16; ++e) os[e] *= al;
        }

        #pragma unroll
        for (int jn = 0; jn < 4; ++jn) {
            u16x4 pk;
            #pragma unroll
            for (int r = 0; r < 4; ++r) pk[r] = f2bf_bits(s[jn][r]);
            int byte = ((il << 7) + (jn << 5) + (g << 3)) ^ ((il & 7) << 4);
            *(u16x4*)((char*)myP + byte) = pk;
        }
        #pragma unroll
        for (int kh = 0; kh < 2; ++kh) {
            bf16x8 pa = lds_frag(myP, il, kh * 4 + g);
            #pragma unroll
            for (int dn = 0; dn < 4; ++dn) {
                bf16x8 bv = lds_frag(Vs[cur], dn * 16 + il, kh * 4 + g);
                o[dn] = __builtin_amdgcn_mfma_f32_16x16x32_bf16(pa, bv, o[dn], 0, 0, 0);
            }
        }
    }

    // ---- epilogue: merge os (row=il, dim split by g) with o fragment ----
    __syncthreads();
    float* osl = (float*)&Ks[0][0] + wv * 1024;  // 16 rows x 64 dims per wave
    #pragma unroll
    for (int kh = 0; kh < 2; ++kh)
        #pragma unroll
        for (int e = 0; e < 8; ++e)
            osl[il * 64 + kh * 32 + g * 8 + e] = os[kh * 8 + e];
    __syncthreads();

    float li[4];
    #pragma unroll
    for (int r = 0; r < 4; ++r) li[r] = 1.0f / __shfl(l, g4 + r);
    #pragma unroll
    for (int dn = 0; dn < 4; ++dn)
        #pragma unroll
        for (int r = 0; r < 4; ++r) {
            int row = i0 + wv * 16 + g4 + r;
            float add = osl[(g4 + r) * 64 + dn * 16 + il];
            O[(size_t)(b * 2048 + row) * 512 + h * 64 + dn * 16 + il] =
                __float2bfloat16((o[dn][r] + add) * li[r]);
        }
}

// ---------------------------------------------------------------------------
// Fused residual add + LayerNorm, vectorized: 4 rows/block (4 waves)
// ---------------------------------------------------------------------------
__global__ __launch_bounds__(256)
void add_ln_kernel(float* __restrict__ X,
                   const __hip_bfloat16* __restrict__ T,
                   const float* __restrict__ g,
                   const float* __restrict__ bb,
                   __hip_bfloat16* __restrict__ Xb) {
    size_t row = blockIdx.x * 4 + (threadIdx.x >> 6);
    int lane = threadIdx.x & 63;
    int d0 = lane * 8;
    float4 x0 = *(const float4*)(X + row * D_ + d0);
    float4 x1 = *(const float4*)(X + row * D_ + d0 + 4);
    u16x8 tv = *(const u16x8*)((const unsigned short*)T + row * D_ + d0);
    float v[8] = { x0.x + bf2f(tv[0]), x0.y + bf2f(tv[1]),
                   x0.z + bf2f(tv[2]), x0.w + bf2f(tv[3]),
                   x1.x + bf2f(tv[4]), x1.y + bf2f(tv[5]),
                   x1.z + bf2f(tv[6]), x1.w + bf2f(tv[7]) };
    float sum = 0.0f;
    #pragma unroll
    for (int q = 0; q < 8; ++q) sum += v[q];
    #pragma unroll
    for (int o = 32; o; o >>= 1) sum += __shfl_xor(sum, o);
    float mean = sum * (1.0f / D_);
    float var = 0.0f;
    #pragma unroll
    for (int q = 0; q < 8; ++q) { float dd = v[q] - mean; var += dd * dd; }
    #pragma unroll
    for (int o = 32; o; o >>= 1) var += __shfl_xor(var, o);
    var *= (1.0f / D_);
    float r = rsqrtf(var + 1e-5f);
    float4 g0 = *(const float4*)(g + d0),  g1 = *(const float4*)(g + d0 + 4);
    float4 b0 = *(const float4*)(bb + d0), b1 = *(const float4*)(bb + d0 + 4);
    float y[8];
    y[0] = (v[0]-mean)*r*g0.x+b0.x; y[1] = (v[1]-mean)*r*g0.y+b0.y;
    y[2] = (v[2]-mean)*r*g0.z+b0.z; y[3] = (v[3]-mean)*r*g0.w+b0.w;
    y[4] = (v[4]-mean)*r*g1.x+b1.x; y[5] = (v[5]-mean)*r*g1.y+b1.y;
    y[6] = (v[6]-mean)*r*g1.z+b1.z; y[7] = (v[7]-mean)*r*g1.w+b1.w;
    *(float4*)(X + row * D_ + d0)     = make_float4(y[0], y[1], y[2], y[3]);
    *(float4*)(X + row * D_ + d0 + 4) = make_float4(y[4], y[5], y[6], y[7]);
    u16x8 pk;
    #pragma unroll
    for (int q = 0; q < 8; ++q) pk[q] = f2bf_bits(y[q]);
    *(u16x8*)((unsigned short*)Xb + row * D_ + d0) = pk;
}

// ---------------------------------------------------------------------------
extern "C" void kernel_launch(void* const* d_in, const int* in_sizes, int n_in,
                              void* d_out, int out_size, void* d_ws, size_t ws_size,
                              hipStream_t stream) {
    const int*   tok   = (const int*)  d_in[0];
    const float* emb   = (const float*)d_in[1];
    const float* b_out = (const float*)d_in[2];
    const float* Wq    = (const float*)d_in[3];
    const float* bq    = (const float*)d_in[4];
    const float* Wk    = (const float*)d_in[5];
    const float* bk    = (const float*)d_in[6];
    const float* Wv    = (const float*)d_in[7];
    const float* bv    = (const float*)d_in[8];
    const float* Wo    = (const float*)d_in[9];
    const float* bo    = (const float*)d_in[10];
    const float* ln1g  = (const float*)d_in[11];
    const float* ln1b  = (const float*)d_in[12];
    const float* W1    = (const float*)d_in[13];
    const float* b1    = (const float*)d_in[14];
    const float* W2    = (const float*)d_in[15];
    const float* b2    = (const float*)d_in[16];
    const float* ln2g  = (const float*)d_in[17];
    const float* ln2b  = (const float*)d_in[18];
    float* out = (float*)d_out;

    char* w = (char*)d_ws;
    auto alloc = [&](size_t bytes) {
        char* p = w;
        w += (bytes + 255) & ~(size_t)255;
        return p;
    };
    float*          X   = (float*)         alloc(XN * 4);
    __hip_bfloat16* Xb  = (__hip_bfloat16*)alloc(XN * 2);
    __hip_bfloat16* Tb  = (__hip_bfloat16*)alloc(XN * 2);
    char* uni = alloc(XN * 2 * 5);
    __hip_bfloat16* Qb  = (__hip_bfloat16*)uni;
    __hip_bfloat16* Kb  = Qb + XN;
    __hip_bfloat16* Vb  = Kb + XN;
    __hip_bfloat16* VTb = Vb + XN;   // [B,H,64,S]
    __hip_bfloat16* Ob  = VTb + XN;
    __hip_bfloat16* Hb  = (__hip_bfloat16*)uni;      // [NTOK, FF] (reuses Qb..VTb)
    __hip_bfloat16* Wqkvt = (__hip_bfloat16*)alloc((size_t)L_ * 1536 * D_ * 2);
    __hip_bfloat16* Wot  = (__hip_bfloat16*)alloc((size_t)L_ * D_ * D_ * 2);
    __hip_bfloat16* W1t  = (__hip_bfloat16*)alloc((size_t)L_ * D_ * FF_ * 2);
    __hip_bfloat16* W2t  = (__hip_bfloat16*)alloc((size_t)L_ * FF_ * D_ * 2);
    __hip_bfloat16* embb = (__hip_bfloat16*)alloc((size_t)V_ * D_ * 2);

    // ---- weight prep ----
    {
        dim3 gqkv(D_ / 32, D_ / 32, L_ * 3);
        transpose_qkv_kernel<<<gqkv, 256, 0, stream>>>(Wq, Wk, Wv, Wqkvt);
        dim3 gdd(D_ / 32, D_ / 32, L_);
        transpose_conv_kernel<<<gdd, 256, 0, stream>>>(Wo, Wot, D_, D_);
        dim3 g1(FF_ / 32, D_ / 32, L_);
        transpose_conv_kernel<<<g1, 256, 0, stream>>>(W1, W1t, D_, FF_);
        dim3 g2(D_ / 32, FF_ / 32, L_);
        transpose_conv_kernel<<<g2, 256, 0, stream>>>(W2, W2t, FF_, D_);
        conv_bf16_kernel<<<(V_ * D_ + 255) / 256, 256, 0, stream>>>(emb, embb, V_ * D_);
    }

    embed_kernel<<<NTOK, 256, 0, stream>>>(tok, emb, X, Xb);

    dim3 blk(256);
    dim3 gqkv(1536 / 128, NTOK / 128);
    dim3 g512(D_ / 128, NTOK / 128);
    dim3 gff (FF_ / 128, NTOK / 128);
    dim3 gout(V_ / 128, NTOK / 128);
    dim3 gattn(S_ / 64, H_, B_);
    dim3 gln(NTOK / 4);

    for (int l = 0; l < L_; ++l) {
        const __hip_bfloat16* wqkv = Wqkvt + (size_t)l * 1536 * D_;
        const __hip_bfloat16* wot = Wot + (size_t)l * D_ * D_;
        const __hip_bfloat16* w1t = W1t + (size_t)l * D_ * FF_;
        const __hip_bfloat16* w2t = W2t + (size_t)l * FF_ * D_;

        gemm_bf16_kernel<0, 4><<<gqkv, blk, 0, stream>>>(
            Xb, wqkv, bq + l * D_, bk + l * D_, bv + l * D_,
            nullptr, Qb, Kb, Vb, VTb, NTOK, 1536, D_);

        attn_mfma_kernel<<<gattn, blk, 0, stream>>>(Qb, Kb, Vb, VTb, Ob);

        gemm_bf16_kernel<0, 1><<<g512, blk, 0, stream>>>(
            Ob, wot, bo + l * D_, nullptr, nullptr,
            nullptr, Tb, nullptr, nullptr, nullptr, NTOK, D_, D_);
        add_ln_kernel<<<gln, blk, 0, stream>>>(X, Tb, ln1g + l * D_, ln1b + l * D_, Xb);

        gemm_bf16_kernel<1, 1><<<gff, blk, 0, stream>>>(
            Xb, w1t, b1 + l * FF_, nullptr, nullptr,
            nullptr, Hb, nullptr, nullptr, nullptr, NTOK, FF_, D_);
        gemm_bf16_kernel<0, 1><<<g512, blk, 0, stream>>>(
            Hb, w2t, b2 + l * D_, nullptr, nullptr,
            nullptr, Tb, nullptr, nullptr, nullptr, NTOK, D_, FF_);
        add_ln_kernel<<<gln, blk, 0, stream>>>(X, Tb, ln2g + l * D_, ln2b + l * D_, Xb);
    }

    gemm_bf16_kernel<0, 0><<<gout, blk, 0, stream>>>(
        Xb, embb, b_out, nullptr, nullptr,
        out, nullptr, nullptr, nullptr, nullptr, NTOK, V_, D_);
}

// Round 5
// 711.085 us; speedup vs baseline: 9.3605x; 1.1959x over previous
//
#include <hip/hip_runtime.h>
#include <hip/hip_bf16.h>
#include <math.h>

// Problem constants
#define B_  4
#define S_  2048
#define D_  512
#define H_  8
#define DH_ 64
#define FF_ 2048
#define L_  4
#define V_  256
#define NTOK (B_ * S_)          // 8192
#define XN  ((size_t)NTOK * D_) // 4,194,304 elems per [B,S,D] buffer

typedef __attribute__((ext_vector_type(8))) short bf16x8;
typedef __attribute__((ext_vector_type(4))) float f32x4;
typedef __attribute__((ext_vector_type(8))) unsigned short u16x8;
typedef __attribute__((ext_vector_type(4))) unsigned short u16x4;

typedef const __attribute__((address_space(1))) unsigned int* gptr_u32;
typedef __attribute__((address_space(3))) unsigned int* lptr_u32;

__device__ __forceinline__ float bf2f(unsigned short u) {
    return __uint_as_float((unsigned)u << 16);
}
__device__ __forceinline__ unsigned short f2bf_bits(float f) {
    __hip_bfloat16 t = __float2bfloat16(f);
    return *(unsigned short*)&t;
}

// ---------------------------------------------------------------------------
// Positional-encoding table: PE[s][d], computed once per launch.
// ---------------------------------------------------------------------------
__global__ void pe_table_kernel(float* __restrict__ PE) {
    int s = blockIdx.x;
    int d = threadIdx.x * 2;              // 256 threads -> d = 0,2,...,510
    float ang = (float)s * expf((float)d * (-logf(10000.0f) / (float)D_));
    PE[(size_t)s * D_ + d]     = sinf(ang);
    PE[(size_t)s * D_ + d + 1] = cosf(ang);
}

// ---------------------------------------------------------------------------
// Embedding + PE lookup -> X fp32 and Xb bf16. grid NTOK, 128 threads.
// ---------------------------------------------------------------------------
__global__ void embed_kernel(const int* __restrict__ tok,
                             const float* __restrict__ emb,
                             const float* __restrict__ PE,
                             float* __restrict__ X,
                             __hip_bfloat16* __restrict__ Xb) {
    int bs = blockIdx.x;
    int s = bs % S_;
    int t = tok[bs];
    const float scale = 22.62741699796952f; // sqrt(512)
    int d = threadIdx.x * 4;
    float4 e = *(const float4*)(emb + (size_t)t * D_ + d);
    float4 p = *(const float4*)(PE + (size_t)s * D_ + d);
    float4 v = make_float4(e.x * scale + p.x, e.y * scale + p.y,
                           e.z * scale + p.z, e.w * scale + p.w);
    *(float4*)(X + (size_t)bs * D_ + d) = v;
    u16x4 pk = { f2bf_bits(v.x), f2bf_bits(v.y), f2bf_bits(v.z), f2bf_bits(v.w) };
    *(u16x4*)((unsigned short*)Xb + (size_t)bs * D_ + d) = pk;
}

// ---------------------------------------------------------------------------
// Weight prep
// ---------------------------------------------------------------------------
__global__ void transpose_conv_kernel(const float* __restrict__ W,
                                      __hip_bfloat16* __restrict__ Wt,
                                      int K, int N) {
    const float* Wl = W + (size_t)blockIdx.z * K * N;
    __hip_bfloat16* Wtl = Wt + (size_t)blockIdx.z * K * N;
    __shared__ float t[32][33];
    int k0 = blockIdx.y * 32, n0 = blockIdx.x * 32;
    int tx = threadIdx.x & 31, ty = threadIdx.x >> 5;
    #pragma unroll
    for (int q = 0; q < 4; ++q)
        t[ty + q * 8][tx] = Wl[(size_t)(k0 + ty + q * 8) * N + n0 + tx];
    __syncthreads();
    #pragma unroll
    for (int q = 0; q < 4; ++q)
        Wtl[(size_t)(n0 + ty + q * 8) * K + k0 + tx] =
            __float2bfloat16(t[tx][ty + q * 8]);
}

// QKV fused: dst[l][1536][512], rows 0-511 Wq^T, 512-1023 Wk^T, 1024-1535 Wv^T
__global__ void transpose_qkv_kernel(const float* __restrict__ Wq,
                                     const float* __restrict__ Wk,
                                     const float* __restrict__ Wv,
                                     __hip_bfloat16* __restrict__ dst) {
    int z = blockIdx.z, l = z / 3, which = z % 3;
    const float* src = (which == 0 ? Wq : which == 1 ? Wk : Wv) + (size_t)l * D_ * D_;
    __hip_bfloat16* d = dst + (size_t)l * 1536 * D_ + (size_t)which * D_ * D_;
    __shared__ float t[32][33];
    int k0 = blockIdx.y * 32, n0 = blockIdx.x * 32;
    int tx = threadIdx.x & 31, ty = threadIdx.x >> 5;
    #pragma unroll
    for (int q = 0; q < 4; ++q)
        t[ty + q * 8][tx] = src[(size_t)(k0 + ty + q * 8) * D_ + n0 + tx];
    __syncthreads();
    #pragma unroll
    for (int q = 0; q < 4; ++q)
        d[(size_t)(n0 + ty + q * 8) * D_ + k0 + tx] =
            __float2bfloat16(t[tx][ty + q * 8]);
}

__global__ void conv_bf16_kernel(const float* __restrict__ in,
                                 __hip_bfloat16* __restrict__ out, int n) {
    int i = blockIdx.x * 256 + threadIdx.x;
    if (i < n) out[i] = __float2bfloat16(in[i]);
}

// ---------------------------------------------------------------------------
// bf16 MFMA GEMM, double-buffered (T3-minimum): C = A[M,K] @ Bt[N,K]^T + bias
// 128x128 tile, BK=32, 256 threads = 4 waves (2x2).
// - next tile's global_load_lds issued BEFORE computing current tile;
//   s_waitcnt vmcnt(4) (counted, not 0) + raw s_barrier -> loads stay in flight.
// - chunk-XOR LDS swizzle (c ^= row&3), pre-swizzled global source + same XOR
//   on ds_read (rule 21) -> bank conflicts 8-way -> <=4-way, coalescing kept.
// - XCD-aware block swizzle (grids here are always %8==0).
// OUT_MODE: 0 = fp32 [M,N]; 1 = bf16 [M,N]; 4 = QKV fused (N=1536):
//   seg 0 -> Cb0 (Q), seg 1 -> Cb1 (K), seg 2 -> Cb2 (V row) + CbT (V^T)
// ---------------------------------------------------------------------------
template <int RELU, int OUT_MODE>
__global__ __launch_bounds__(256)
void gemm_bf16_kernel(const __hip_bfloat16* __restrict__ A,
                      const __hip_bfloat16* __restrict__ Bt,
                      const float* __restrict__ bias0,
                      const float* __restrict__ bias1,
                      const float* __restrict__ bias2,
                      float* __restrict__ Cf,
                      __hip_bfloat16* __restrict__ Cb0,
                      __hip_bfloat16* __restrict__ Cb1,
                      __hip_bfloat16* __restrict__ Cb2,
                      __hip_bfloat16* __restrict__ CbT,
                      int M, int N, int K) {
    __shared__ unsigned short As[2][128 * 32];
    __shared__ unsigned short Bs[2][128 * 32];
    int tid = threadIdx.x;
    int lane = tid & 63, wid = tid >> 6;
    int wm = (wid >> 1) * 64, wn = (wid & 1) * 64;
    int g = lane >> 4, il = lane & 15;

    // XCD-aware swizzle: contiguous chunk of flat ids per XCD
    int gx = gridDim.x;
    int fid = blockIdx.x + gx * blockIdx.y;
    int cpx = (gx * gridDim.y) >> 3;
    int swz = (fid & 7) * cpx + (fid >> 3);
    int m0 = (swz / gx) * 128, n0 = (swz % gx) * 128;

    auto stage = [&](int buf, int k0) {
        #pragma unroll
        for (int q = 0; q < 2; ++q) {
            int idx = q * 256 + tid;
            int r = idx >> 2, c = idx & 3;
            int csw = (c ^ r) & 3;                 // chunk swizzle
            const __hip_bfloat16* sa = A + (size_t)(m0 + r) * K + k0 + csw * 8;
            __builtin_amdgcn_global_load_lds((gptr_u32)(const void*)sa,
                                             (lptr_u32)(void*)&As[buf][idx * 8], 16, 0, 0);
            const __hip_bfloat16* sb = Bt + (size_t)(n0 + r) * K + k0 + csw * 8;
            __builtin_amdgcn_global_load_lds((gptr_u32)(const void*)sb,
                                             (lptr_u32)(void*)&Bs[buf][idx * 8], 16, 0, 0);
        }
    };

    f32x4 acc[4][4] = {};
    int NT = K >> 5;
    stage(0, 0);

    for (int t = 0; t < NT; ++t) {
        int cur = t & 1;
        if (t + 1 < NT) {
            stage(cur ^ 1, (t + 1) << 5);
            asm volatile("s_waitcnt vmcnt(4)" ::: "memory");  // current tile done, next in flight
        } else {
            asm volatile("s_waitcnt vmcnt(0)" ::: "memory");
        }
        __builtin_amdgcn_s_barrier();

        bf16x8 af[4], bf[4];
        #pragma unroll
        for (int i = 0; i < 4; ++i) {
            int m = wm + i * 16 + il;
            af[i] = *(const bf16x8*)&As[cur][m * 32 + ((g ^ m) & 3) * 8];
            int n = wn + i * 16 + il;
            bf[i] = *(const bf16x8*)&Bs[cur][n * 32 + ((g ^ n) & 3) * 8];
        }
        #pragma unroll
        for (int i = 0; i < 4; ++i)
            #pragma unroll
            for (int j = 0; j < 4; ++j)
                acc[i][j] = __builtin_amdgcn_mfma_f32_16x16x32_bf16(
                    af[i], bf[j], acc[i][j], 0, 0, 0);

        __builtin_amdgcn_s_barrier();   // all waves done reading before overwrite
    }

    // C/D layout: col = lane&15, row = (lane>>4)*4 + reg
    if (OUT_MODE == 4) {
        int seg = n0 >> 9;                       // block-uniform
        const float* bias = seg == 0 ? bias0 : seg == 1 ? bias1 : bias2;
        __hip_bfloat16* Crow = seg == 0 ? Cb0 : seg == 1 ? Cb1 : Cb2;
        int nseg = n0 & 511;
        #pragma unroll
        for (int j = 0; j < 4; ++j) {
            int coll = nseg + wn + j * 16 + il;
            float bv = bias[coll];
            #pragma unroll
            for (int i = 0; i < 4; ++i) {
                int row0 = m0 + wm + i * 16 + g * 4;
                if (seg < 2) {
                    #pragma unroll
                    for (int r = 0; r < 4; ++r)
                        Crow[(size_t)(row0 + r) * 512 + coll] =
                            __float2bfloat16(acc[i][j][r] + bv);
                } else {
                    u16x4 pk;
                    #pragma unroll
                    for (int r = 0; r < 4; ++r) {
                        float v = acc[i][j][r] + bv;
                        Crow[(size_t)(row0 + r) * 512 + coll] = __float2bfloat16(v);
                        pk[r] = f2bf_bits(v);
                    }
                    int hh = coll >> 6, dh = coll & 63;
                    int bb = row0 >> 11, s0 = row0 & 2047;
                    *(u16x4*)(CbT + ((size_t)((bb * 8 + hh) * 64 + dh) * 2048 + s0)) = pk;
                }
            }
        }
    } else {
        #pragma unroll
        for (int j = 0; j < 4; ++j) {
            int col = n0 + wn + j * 16 + il;
            float bv = bias0[col];
            #pragma unroll
            for (int i = 0; i < 4; ++i) {
                #pragma unroll
                for (int r = 0; r < 4; ++r) {
                    int row = m0 + wm + i * 16 + g * 4 + r;
                    float v = acc[i][j][r] + bv;
                    if (RELU) v = fmaxf(v, 0.0f);
                    if (OUT_MODE == 1) Cb0[(size_t)row * N + col] = __float2bfloat16(v);
                    else               Cf[(size_t)row * N + col] = v;
                }
            }
        }
    }
}

// ---------------------------------------------------------------------------
// MFMA block-sparse flash attention (v2 + XCD swizzle).
// MFMA tiles: local {i0-64k} + (i0>256 ? tile0 (j<16) : none); strided keys
// via per-lane diagonal dot phase. Softmax in exp2 domain, skip-rescale.
// XCD swizzle: all 32 q-tiles of one (b,h) cluster on one XCD (K/V L2 reuse).
// ---------------------------------------------------------------------------
__device__ __forceinline__ bf16x8 lds_frag(const unsigned short* base, int row, int chunk) {
    int byte = (row << 7) + (((chunk ^ (row & 7)) & 7) << 4);
    return *(const bf16x8*)((const char*)base + byte);
}

__global__ __launch_bounds__(256)
void attn_mfma_kernel(const __hip_bfloat16* __restrict__ Q,   // [NTOK][512]
                      const __hip_bfloat16* __restrict__ K,   // [NTOK][512]
                      const __hip_bfloat16* __restrict__ V,   // [NTOK][512]
                      const __hip_bfloat16* __restrict__ VT,  // [B*H*64][2048]
                      __hip_bfloat16* __restrict__ O) {       // [NTOK][512]
    __shared__ unsigned short Ks[2][64 * 64];
    __shared__ unsigned short Vs[2][64 * 64];
    __shared__ unsigned short Ps[4][16 * 64];

    // XCD swizzle: flat id -> (q, h, b) with q-tiles of one (b,h) contiguous per XCD
    int fid = blockIdx.x + 32 * (blockIdx.y + 8 * blockIdx.z);  // 0..1023
    int swz = (fid & 7) * 128 + (fid >> 3);
    int i0 = (swz & 31) * 64;
    int h  = (swz >> 5) & 7;
    int b  = swz >> 8;

    int tid = threadIdx.x, lane = tid & 63, wv = tid >> 6;
    int g = lane >> 4, il = lane & 15, g4 = g * 4;

    int nloc = min(i0 >> 6, 4) + 1;
    int add0 = (i0 > 256);
    int nt = nloc + add0;

    const size_t vt_off = (size_t)((b * 8 + h) * 64) * 2048;
    auto j0_of = [&](int t) { return (t < nloc) ? (i0 - 64 * t) : 0; };

    auto stage = [&](int buf, int j0) {
        #pragma unroll
        for (int q = 0; q < 2; ++q) {
            int idx = q * 256 + tid;
            int row = idx >> 3, c = idx & 7;
            int csw = c ^ (row & 7);
            const __hip_bfloat16* sk = K + (size_t)(b * 2048 + j0 + row) * 512 + h * 64 + csw * 8;
            __builtin_amdgcn_global_load_lds((gptr_u32)(const void*)sk,
                                             (lptr_u32)(void*)&Ks[buf][idx * 8], 16, 0, 0);
            const __hip_bfloat16* sv = VT + vt_off + (size_t)row * 2048 + j0 + csw * 8;
            __builtin_amdgcn_global_load_lds((gptr_u32)(const void*)sv,
                                             (lptr_u32)(void*)&Vs[buf][idx * 8], 16, 0, 0);
        }
    };

    int iq = i0 + wv * 16 + il;
    bf16x8 qf[2];
    #pragma unroll
    for (int kh = 0; kh < 2; ++kh)
        qf[kh] = *(const bf16x8*)(Q + (size_t)(b * 2048 + iq) * 512 + h * 64 + kh * 32 + g * 8);

    stage(0, j0_of(0));   // overlap first tile load with scalar phase

    float qfl[16];
    #pragma unroll
    for (int kh = 0; kh < 2; ++kh)
        #pragma unroll
        for (int e = 0; e < 8; ++e)
            qfl[kh * 8 + e] = bf2f(((u16x8)qf[kh])[e]);

    unsigned short* myP = Ps[wv];
    f32x4 o[4] = {};
    float os[16] = {};
    float m = -1e30f, l = 0.0f;
    const float CSC = 0.18033688011112042f; // 0.125 * log2(e)

    // ---- scalar strided phase ----
    const unsigned short* Kbase = (const unsigned short*)(K + (size_t)b * 2048 * 512 + h * 64);
    const unsigned short* Vbase = (const unsigned short*)(V + (size_t)b * 2048 * 512 + h * 64);
    for (int j = iq - 384; j >= 16; j -= 128) {
        const unsigned short* kr = Kbase + (size_t)j * 512;
        u16x8 k0 = *(const u16x8*)(kr + g * 8);
        u16x8 k1 = *(const u16x8*)(kr + 32 + g * 8);
        float dot = 0.0f;
        #pragma unroll
        for (int e = 0; e < 8; ++e)
            dot += qfl[e] * bf2f(k0[e]) + qfl[8 + e] * bf2f(k1[e]);
        dot += __shfl_xor(dot, 16);
        dot += __shfl_xor(dot, 32);
        float s2 = dot * CSC;
        float mn = fmaxf(m, s2);
        float al = exp2f(m - mn);
        float p = exp2f(s2 - mn);
        l = l * al + p;
        m = mn;
        const unsigned short* vr = Vbase + (size_t)j * 512;
        u16x8 v0 = *(const u16x8*)(vr + g * 8);
        u16x8 v1 = *(const u16x8*)(vr + 32 + g * 8);
        #pragma unroll
        for (int e = 0; e < 8; ++e) {
            os[e]     = os[e]     * al + p * bf2f(v0[e]);
            os[8 + e] = os[8 + e] * al + p * bf2f(v1[e]);
        }
    }

    // ---- MFMA tile phase ----
    for (int t = 0; t < nt; ++t) {
        __syncthreads();
        int cur = t & 1;
        if (t + 1 < nt) stage(cur ^ 1, j0_of(t + 1));
        int j0 = j0_of(t);

        f32x4 s[4] = {};
        #pragma unroll
        for (int kh = 0; kh < 2; ++kh)
            #pragma unroll
            for (int jn = 0; jn < 4; ++jn) {
                bf16x8 a = lds_frag(Ks[cur], jn * 16 + il, kh * 4 + g);
                s[jn] = __builtin_amdgcn_mfma_f32_16x16x32_bf16(a, qf[kh], s[jn], 0, 0, 0);
            }

        float mloc = -1e30f;
        if (t >= nloc) {           // global tile: j<16 only
            #pragma unroll
            for (int jn = 0; jn < 4; ++jn)
                #pragma unroll
                for (int r = 0; r < 4; ++r) {
                    int jg = jn * 16 + g4 + r;
                    float sv = (jg < 16) ? s[jn][r] * CSC : -1e30f;
                    s[jn][r] = sv;
                    mloc = fmaxf(mloc, sv);
                }
        } else if (t == 0) {       // diagonal: causal
            #pragma unroll
            for (int jn = 0; jn < 4; ++jn)
                #pragma unroll
                for (int r = 0; r < 4; ++r) {
                    int jg = j0 + jn * 16 + g4 + r;
                    float sv = (iq >= jg) ? s[jn][r] * CSC : -1e30f;
                    s[jn][r] = sv;
                    mloc = fmaxf(mloc, sv);
                }
        } else if (t == 4) {       // window edge: local | strided | global
            #pragma unroll
            for (int jn = 0; jn < 4; ++jn)
                #pragma unroll
                for (int r = 0; r < 4; ++r) {
                    int jg = j0 + jn * 16 + g4 + r;
                    int dij = iq - jg;
                    bool ok = (dij < 256) || ((dij & 127) == 0) || (jg < 16);
                    float sv = ok ? s[jn][r] * CSC : -1e30f;
                    s[jn][r] = sv;
                    mloc = fmaxf(mloc, sv);
                }
        } else {                   // fully inside window
            #pragma unroll
            for (int jn = 0; jn < 4; ++jn)
                #pragma unroll
                for (int r = 0; r < 4; ++r) {
                    float sv = s[jn][r] * CSC;
                    s[jn][r] = sv;
                    mloc = fmaxf(mloc, sv);
                }
        }
        mloc = fmaxf(mloc, __shfl_xor(mloc, 16));
        mloc = fmaxf(mloc, __shfl_xor(mloc, 32));
        float mn = fmaxf(m, mloc);
        float al = exp2f(m - mn);

        float lloc = 0.0f;
        #pragma unroll
        for (int jn = 0; jn < 4; ++jn)
            #pragma unroll
            for (int r = 0; r < 4; ++r) {
                float p = exp2f(s[jn][r] - mn);
                s[jn][r] = p;
                lloc += p;
            }
        lloc += __shfl_xor(lloc, 16);
        lloc += __shfl_xor(lloc, 32);
        l = l * al + lloc;
        m = mn;

        if (!__all(al == 1.0f)) {
            float ar[4];
            #pragma unroll
            for (int r = 0; r < 4; ++r) ar[r] = __shfl(al, g4 + r);
            #pragma unroll
            for (int dn = 0; dn < 4; ++dn)
                #pragma unroll
                for (int r = 0; r < 4; ++r) o[dn][r] *= ar[r];
            #pragma unroll
            for (int e = 0; e < 16; ++e) os[e] *= al;
        }

        #pragma unroll
        for (int jn = 0; jn < 4; ++jn) {
            u16x4 pk;
            #pragma unroll
            for (int r = 0; r < 4; ++r) pk[r] = f2bf_bits(s[jn][r]);
            int byte = ((il << 7) + (jn << 5) + (g << 3)) ^ ((il & 7) << 4);
            *(u16x4*)((char*)myP + byte) = pk;
        }
        #pragma unroll
        for (int kh = 0; kh < 2; ++kh) {
            bf16x8 pa = lds_frag(myP, il, kh * 4 + g);
            #pragma unroll
            for (int dn = 0; dn < 4; ++dn) {
                bf16x8 bv = lds_frag(Vs[cur], dn * 16 + il, kh * 4 + g);
                o[dn] = __builtin_amdgcn_mfma_f32_16x16x32_bf16(pa, bv, o[dn], 0, 0, 0);
            }
        }
    }

    // ---- epilogue: merge os (row=il, dim split by g) with o fragment ----
    __syncthreads();
    float* osl = (float*)&Ks[0][0] + wv * 1024;  // 16 rows x 64 dims per wave
    #pragma unroll
    for (int kh = 0; kh < 2; ++kh)
        #pragma unroll
        for (int e = 0; e < 8; ++e)
            osl[il * 64 + kh * 32 + g * 8 + e] = os[kh * 8 + e];
    __syncthreads();

    float li[4];
    #pragma unroll
    for (int r = 0; r < 4; ++r) li[r] = 1.0f / __shfl(l, g4 + r);
    #pragma unroll
    for (int dn = 0; dn < 4; ++dn)
        #pragma unroll
        for (int r = 0; r < 4; ++r) {
            int row = i0 + wv * 16 + g4 + r;
            float add = osl[(g4 + r) * 64 + dn * 16 + il];
            O[(size_t)(b * 2048 + row) * 512 + h * 64 + dn * 16 + il] =
                __float2bfloat16((o[dn][r] + add) * li[r]);
        }
}

// ---------------------------------------------------------------------------
// Fused residual add + LayerNorm, vectorized: 4 rows/block (4 waves)
// ---------------------------------------------------------------------------
__global__ __launch_bounds__(256)
void add_ln_kernel(float* __restrict__ X,
                   const __hip_bfloat16* __restrict__ T,
                   const float* __restrict__ g,
                   const float* __restrict__ bb,
                   __hip_bfloat16* __restrict__ Xb) {
    size_t row = blockIdx.x * 4 + (threadIdx.x >> 6);
    int lane = threadIdx.x & 63;
    int d0 = lane * 8;
    float4 x0 = *(const float4*)(X + row * D_ + d0);
    float4 x1 = *(const float4*)(X + row * D_ + d0 + 4);
    u16x8 tv = *(const u16x8*)((const unsigned short*)T + row * D_ + d0);
    float v[8] = { x0.x + bf2f(tv[0]), x0.y + bf2f(tv[1]),
                   x0.z + bf2f(tv[2]), x0.w + bf2f(tv[3]),
                   x1.x + bf2f(tv[4]), x1.y + bf2f(tv[5]),
                   x1.z + bf2f(tv[6]), x1.w + bf2f(tv[7]) };
    float sum = 0.0f;
    #pragma unroll
    for (int q = 0; q < 8; ++q) sum += v[q];
    #pragma unroll
    for (int o = 32; o; o >>= 1) sum += __shfl_xor(sum, o);
    float mean = sum * (1.0f / D_);
    float var = 0.0f;
    #pragma unroll
    for (int q = 0; q < 8; ++q) { float dd = v[q] - mean; var += dd * dd; }
    #pragma unroll
    for (int o = 32; o; o >>= 1) var += __shfl_xor(var, o);
    var *= (1.0f / D_);
    float r = rsqrtf(var + 1e-5f);
    float4 g0 = *(const float4*)(g + d0),  g1 = *(const float4*)(g + d0 + 4);
    float4 b0 = *(const float4*)(bb + d0), b1 = *(const float4*)(bb + d0 + 4);
    float y[8];
    y[0] = (v[0]-mean)*r*g0.x+b0.x; y[1] = (v[1]-mean)*r*g0.y+b0.y;
    y[2] = (v[2]-mean)*r*g0.z+b0.z; y[3] = (v[3]-mean)*r*g0.w+b0.w;
    y[4] = (v[4]-mean)*r*g1.x+b1.x; y[5] = (v[5]-mean)*r*g1.y+b1.y;
    y[6] = (v[6]-mean)*r*g1.z+b1.z; y[7] = (v[7]-mean)*r*g1.w+b1.w;
    *(float4*)(X + row * D_ + d0)     = make_float4(y[0], y[1], y[2], y[3]);
    *(float4*)(X + row * D_ + d0 + 4) = make_float4(y[4], y[5], y[6], y[7]);
    u16x8 pk;
    #pragma unroll
    for (int q = 0; q < 8; ++q) pk[q] = f2bf_bits(y[q]);
    *(u16x8*)((unsigned short*)Xb + row * D_ + d0) = pk;
}

// ---------------------------------------------------------------------------
extern "C" void kernel_launch(void* const* d_in, const int* in_sizes, int n_in,
                              void* d_out, int out_size, void* d_ws, size_t ws_size,
                              hipStream_t stream) {
    const int*   tok   = (const int*)  d_in[0];
    const float* emb   = (const float*)d_in[1];
    const float* b_out = (const float*)d_in[2];
    const float* Wq    = (const float*)d_in[3];
    const float* bq    = (const float*)d_in[4];
    const float* Wk    = (const float*)d_in[5];
    const float* bk    = (const float*)d_in[6];
    const float* Wv    = (const float*)d_in[7];
    const float* bv    = (const float*)d_in[8];
    const float* Wo    = (const float*)d_in[9];
    const float* bo    = (const float*)d_in[10];
    const float* ln1g  = (const float*)d_in[11];
    const float* ln1b  = (const float*)d_in[12];
    const float* W1    = (const float*)d_in[13];
    const float* b1    = (const float*)d_in[14];
    const float* W2    = (const float*)d_in[15];
    const float* b2    = (const float*)d_in[16];
    const float* ln2g  = (const float*)d_in[17];
    const float* ln2b  = (const float*)d_in[18];
    float* out = (float*)d_out;

    char* w = (char*)d_ws;
    auto alloc = [&](size_t bytes) {
        char* p = w;
        w += (bytes + 255) & ~(size_t)255;
        return p;
    };
    float*          X   = (float*)         alloc(XN * 4);
    __hip_bfloat16* Xb  = (__hip_bfloat16*)alloc(XN * 2);
    __hip_bfloat16* Tb  = (__hip_bfloat16*)alloc(XN * 2);
    char* uni = alloc(XN * 2 * 5);
    __hip_bfloat16* Qb  = (__hip_bfloat16*)uni;
    __hip_bfloat16* Kb  = Qb + XN;
    __hip_bfloat16* Vb  = Kb + XN;
    __hip_bfloat16* VTb = Vb + XN;   // [B,H,64,S]
    __hip_bfloat16* Ob  = VTb + XN;
    __hip_bfloat16* Hb  = (__hip_bfloat16*)uni;      // [NTOK, FF] (reuses Qb..VTb)
    __hip_bfloat16* Wqkvt = (__hip_bfloat16*)alloc((size_t)L_ * 1536 * D_ * 2);
    __hip_bfloat16* Wot  = (__hip_bfloat16*)alloc((size_t)L_ * D_ * D_ * 2);
    __hip_bfloat16* W1t  = (__hip_bfloat16*)alloc((size_t)L_ * D_ * FF_ * 2);
    __hip_bfloat16* W2t  = (__hip_bfloat16*)alloc((size_t)L_ * FF_ * D_ * 2);
    __hip_bfloat16* embb = (__hip_bfloat16*)alloc((size_t)V_ * D_ * 2);
    float*          PE   = (float*)alloc((size_t)S_ * D_ * 4);

    // ---- prep ----
    {
        pe_table_kernel<<<S_, 256, 0, stream>>>(PE);
        dim3 gqkv(D_ / 32, D_ / 32, L_ * 3);
        transpose_qkv_kernel<<<gqkv, 256, 0, stream>>>(Wq, Wk, Wv, Wqkvt);
        dim3 gdd(D_ / 32, D_ / 32, L_);
        transpose_conv_kernel<<<gdd, 256, 0, stream>>>(Wo, Wot, D_, D_);
        dim3 g1(FF_ / 32, D_ / 32, L_);
        transpose_conv_kernel<<<g1, 256, 0, stream>>>(W1, W1t, D_, FF_);
        dim3 g2(D_ / 32, FF_ / 32, L_);
        transpose_conv_kernel<<<g2, 256, 0, stream>>>(W2, W2t, FF_, D_);
        conv_bf16_kernel<<<(V_ * D_ + 255) / 256, 256, 0, stream>>>(emb, embb, V_ * D_);
    }

    embed_kernel<<<NTOK, 128, 0, stream>>>(tok, emb, PE, X, Xb);

    dim3 blk(256);
    dim3 gqkv(1536 / 128, NTOK / 128);
    dim3 g512(D_ / 128, NTOK / 128);
    dim3 gff (FF_ / 128, NTOK / 128);
    dim3 gout(V_ / 128, NTOK / 128);
    dim3 gattn(S_ / 64, H_, B_);
    dim3 gln(NTOK / 4);

    for (int l = 0; l < L_; ++l) {
        const __hip_bfloat16* wqkv = Wqkvt + (size_t)l * 1536 * D_;
        const __hip_bfloat16* wot = Wot + (size_t)l * D_ * D_;
        const __hip_bfloat16* w1t = W1t + (size_t)l * D_ * FF_;
        const __hip_bfloat16* w2t = W2t + (size_t)l * FF_ * D_;

        gemm_bf16_kernel<0, 4><<<gqkv, blk, 0, stream>>>(
            Xb, wqkv, bq + l * D_, bk + l * D_, bv + l * D_,
            nullptr, Qb, Kb, Vb, VTb, NTOK, 1536, D_);

        attn_mfma_kernel<<<gattn, blk, 0, stream>>>(Qb, Kb, Vb, VTb, Ob);

        gemm_bf16_kernel<0, 1><<<g512, blk, 0, stream>>>(
            Ob, wot, bo + l * D_, nullptr, nullptr,
            nullptr, Tb, nullptr, nullptr, nullptr, NTOK, D_, D_);
        add_ln_kernel<<<gln, blk, 0, stream>>>(X, Tb, ln1g + l * D_, ln1b + l * D_, Xb);

        gemm_bf16_kernel<1, 1><<<gff, blk, 0, stream>>>(
            Xb, w1t, b1 + l * FF_, nullptr, nullptr,
            nullptr, Hb, nullptr, nullptr, nullptr, NTOK, FF_, D_);
        gemm_bf16_kernel<0, 1><<<g512, blk, 0, stream>>>(
            Hb, w2t, b2 + l * D_, nullptr, nullptr,
            nullptr, Tb, nullptr, nullptr, nullptr, NTOK, D_, FF_);
        add_ln_kernel<<<gln, blk, 0, stream>>>(X, Tb, ln2g + l * D_, ln2b + l * D_, Xb);
    }

    gemm_bf16_kernel<0, 0><<<gout, blk, 0, stream>>>(
        Xb, embb, b_out, nullptr, nullptr,
        out, nullptr, nullptr, nullptr, nullptr, NTOK, V_, D_);
}

// Round 6
// 692.484 us; speedup vs baseline: 9.6119x; 1.0269x over previous
//
#include <hip/hip_runtime.h>
#include <hip/hip_bf16.h>
#include <math.h>

// Problem constants
#define B_  4
#define S_  2048
#define D_  512
#define H_  8
#define DH_ 64
#define FF_ 2048
#define L_  4
#define V_  256
#define NTOK (B_ * S_)          // 8192
#define XN  ((size_t)NTOK * D_) // 4,194,304 elems per [B,S,D] buffer

typedef __attribute__((ext_vector_type(8))) short bf16x8;
typedef __attribute__((ext_vector_type(4))) float f32x4;
typedef __attribute__((ext_vector_type(8))) unsigned short u16x8;
typedef __attribute__((ext_vector_type(4))) unsigned short u16x4;

typedef const __attribute__((address_space(1))) unsigned int* gptr_u32;
typedef __attribute__((address_space(3))) unsigned int* lptr_u32;

__device__ __forceinline__ float bf2f(unsigned short u) {
    return __uint_as_float((unsigned)u << 16);
}
__device__ __forceinline__ unsigned short f2bf_bits(float f) {
    __hip_bfloat16 t = __float2bfloat16(f);
    return *(unsigned short*)&t;
}

// ---------------------------------------------------------------------------
// Positional-encoding table: PE[s][d], computed once per launch.
// ---------------------------------------------------------------------------
__global__ void pe_table_kernel(float* __restrict__ PE) {
    int s = blockIdx.x;
    int d = threadIdx.x * 2;              // 256 threads -> d = 0,2,...,510
    float ang = (float)s * expf((float)d * (-logf(10000.0f) / (float)D_));
    PE[(size_t)s * D_ + d]     = sinf(ang);
    PE[(size_t)s * D_ + d + 1] = cosf(ang);
}

// ---------------------------------------------------------------------------
// Embedding + PE lookup -> X fp32 and Xb bf16. grid NTOK, 128 threads.
// ---------------------------------------------------------------------------
__global__ void embed_kernel(const int* __restrict__ tok,
                             const float* __restrict__ emb,
                             const float* __restrict__ PE,
                             float* __restrict__ X,
                             __hip_bfloat16* __restrict__ Xb) {
    int bs = blockIdx.x;
    int s = bs % S_;
    int t = tok[bs];
    const float scale = 22.62741699796952f; // sqrt(512)
    int d = threadIdx.x * 4;
    float4 e = *(const float4*)(emb + (size_t)t * D_ + d);
    float4 p = *(const float4*)(PE + (size_t)s * D_ + d);
    float4 v = make_float4(e.x * scale + p.x, e.y * scale + p.y,
                           e.z * scale + p.z, e.w * scale + p.w);
    *(float4*)(X + (size_t)bs * D_ + d) = v;
    u16x4 pk = { f2bf_bits(v.x), f2bf_bits(v.y), f2bf_bits(v.z), f2bf_bits(v.w) };
    *(u16x4*)((unsigned short*)Xb + (size_t)bs * D_ + d) = pk;
}

// ---------------------------------------------------------------------------
// Weight prep
// ---------------------------------------------------------------------------
__global__ void transpose_conv_kernel(const float* __restrict__ W,
                                      __hip_bfloat16* __restrict__ Wt,
                                      int K, int N) {
    const float* Wl = W + (size_t)blockIdx.z * K * N;
    __hip_bfloat16* Wtl = Wt + (size_t)blockIdx.z * K * N;
    __shared__ float t[32][33];
    int k0 = blockIdx.y * 32, n0 = blockIdx.x * 32;
    int tx = threadIdx.x & 31, ty = threadIdx.x >> 5;
    #pragma unroll
    for (int q = 0; q < 4; ++q)
        t[ty + q * 8][tx] = Wl[(size_t)(k0 + ty + q * 8) * N + n0 + tx];
    __syncthreads();
    #pragma unroll
    for (int q = 0; q < 4; ++q)
        Wtl[(size_t)(n0 + ty + q * 8) * K + k0 + tx] =
            __float2bfloat16(t[tx][ty + q * 8]);
}

// QKV fused: dst[l][1536][512], rows 0-511 Wq^T, 512-1023 Wk^T, 1024-1535 Wv^T
__global__ void transpose_qkv_kernel(const float* __restrict__ Wq,
                                     const float* __restrict__ Wk,
                                     const float* __restrict__ Wv,
                                     __hip_bfloat16* __restrict__ dst) {
    int z = blockIdx.z, l = z / 3, which = z % 3;
    const float* src = (which == 0 ? Wq : which == 1 ? Wk : Wv) + (size_t)l * D_ * D_;
    __hip_bfloat16* d = dst + (size_t)l * 1536 * D_ + (size_t)which * D_ * D_;
    __shared__ float t[32][33];
    int k0 = blockIdx.y * 32, n0 = blockIdx.x * 32;
    int tx = threadIdx.x & 31, ty = threadIdx.x >> 5;
    #pragma unroll
    for (int q = 0; q < 4; ++q)
        t[ty + q * 8][tx] = src[(size_t)(k0 + ty + q * 8) * D_ + n0 + tx];
    __syncthreads();
    #pragma unroll
    for (int q = 0; q < 4; ++q)
        d[(size_t)(n0 + ty + q * 8) * D_ + k0 + tx] =
            __float2bfloat16(t[tx][ty + q * 8]);
}

__global__ void conv_bf16_kernel(const float* __restrict__ in,
                                 __hip_bfloat16* __restrict__ out, int n) {
    int i = blockIdx.x * 256 + threadIdx.x;
    if (i < n) out[i] = __float2bfloat16(in[i]);
}

// ---------------------------------------------------------------------------
// bf16 MFMA GEMM, double-buffered, tileable: C = A[M,K] @ Bt[N,K]^T + bias
// BM = 128 (4 waves x 64x64) or 64 (4 waves x 32x64, for narrow-N GEMMs ->
// 2x grid, 2 blocks/CU). BN=128, BK=32. Counted vmcnt keeps next tile's
// global_load_lds in flight across the barrier.
// OUT_MODE: 0 = fp32 [M,N]; 1 = bf16 [M,N]; 4 = QKV fused (N=1536):
//   seg 0 -> Cb0 (Q), seg 1 -> Cb1 (K), seg 2 -> Cb2 (V row) + CbT (V^T)
// ---------------------------------------------------------------------------
template <int BM, int RELU, int OUT_MODE>
__global__ __launch_bounds__(256)
void gemm_bf16_kernel(const __hip_bfloat16* __restrict__ A,
                      const __hip_bfloat16* __restrict__ Bt,
                      const float* __restrict__ bias0,
                      const float* __restrict__ bias1,
                      const float* __restrict__ bias2,
                      float* __restrict__ Cf,
                      __hip_bfloat16* __restrict__ Cb0,
                      __hip_bfloat16* __restrict__ Cb1,
                      __hip_bfloat16* __restrict__ Cb2,
                      __hip_bfloat16* __restrict__ CbT,
                      int M, int N, int K) {
    constexpr int MI = BM / 32;              // M-fragments per wave
    __shared__ unsigned short As[2][BM * 32];
    __shared__ unsigned short Bs[2][128 * 32];
    int tid = threadIdx.x;
    int lane = tid & 63, wid = tid >> 6;
    int wm = (wid >> 1) * (BM / 2), wn = (wid & 1) * 64;
    int g = lane >> 4, il = lane & 15;

    // XCD-aware swizzle: contiguous chunk of flat ids per XCD (grid % 8 == 0)
    int gx = gridDim.x;
    int fid = blockIdx.x + gx * blockIdx.y;
    int cpx = (gx * gridDim.y) >> 3;
    int swz = (fid & 7) * cpx + (fid >> 3);
    int m0 = (swz / gx) * BM, n0 = (swz % gx) * 128;

    auto stage = [&](int buf, int k0) {
        #pragma unroll
        for (int q = 0; q < BM / 64; ++q) {
            int idx = q * 256 + tid;
            int r = idx >> 2, c = idx & 3;
            int csw = (c ^ r) & 3;
            const __hip_bfloat16* sa = A + (size_t)(m0 + r) * K + k0 + csw * 8;
            __builtin_amdgcn_global_load_lds((gptr_u32)(const void*)sa,
                                             (lptr_u32)(void*)&As[buf][idx * 8], 16, 0, 0);
        }
        #pragma unroll
        for (int q = 0; q < 2; ++q) {
            int idx = q * 256 + tid;
            int r = idx >> 2, c = idx & 3;
            int csw = (c ^ r) & 3;
            const __hip_bfloat16* sb = Bt + (size_t)(n0 + r) * K + k0 + csw * 8;
            __builtin_amdgcn_global_load_lds((gptr_u32)(const void*)sb,
                                             (lptr_u32)(void*)&Bs[buf][idx * 8], 16, 0, 0);
        }
    };

    f32x4 acc[MI][4] = {};
    int NT = K >> 5;
    stage(0, 0);

    for (int t = 0; t < NT; ++t) {
        int cur = t & 1;
        if (t + 1 < NT) {
            stage(cur ^ 1, (t + 1) << 5);
            if constexpr (BM == 128)
                asm volatile("s_waitcnt vmcnt(4)" ::: "memory");
            else
                asm volatile("s_waitcnt vmcnt(3)" ::: "memory");
        } else {
            asm volatile("s_waitcnt vmcnt(0)" ::: "memory");
        }
        __builtin_amdgcn_s_barrier();

        bf16x8 af[MI], bf[4];
        #pragma unroll
        for (int i = 0; i < MI; ++i) {
            int m = wm + i * 16 + il;
            af[i] = *(const bf16x8*)&As[cur][m * 32 + ((g ^ m) & 3) * 8];
        }
        #pragma unroll
        for (int j = 0; j < 4; ++j) {
            int n = wn + j * 16 + il;
            bf[j] = *(const bf16x8*)&Bs[cur][n * 32 + ((g ^ n) & 3) * 8];
        }
        #pragma unroll
        for (int i = 0; i < MI; ++i)
            #pragma unroll
            for (int j = 0; j < 4; ++j)
                acc[i][j] = __builtin_amdgcn_mfma_f32_16x16x32_bf16(
                    af[i], bf[j], acc[i][j], 0, 0, 0);

        __builtin_amdgcn_s_barrier();   // all waves done reading before overwrite
    }

    // C/D layout: col = lane&15, row = (lane>>4)*4 + reg
    if constexpr (OUT_MODE == 4) {
        int seg = n0 >> 9;                       // block-uniform
        const float* bias = seg == 0 ? bias0 : seg == 1 ? bias1 : bias2;
        __hip_bfloat16* Crow = seg == 0 ? Cb0 : seg == 1 ? Cb1 : Cb2;
        int nseg = n0 & 511;
        #pragma unroll
        for (int j = 0; j < 4; ++j) {
            int coll = nseg + wn + j * 16 + il;
            float bv = bias[coll];
            #pragma unroll
            for (int i = 0; i < MI; ++i) {
                int row0 = m0 + wm + i * 16 + g * 4;
                if (seg < 2) {
                    #pragma unroll
                    for (int r = 0; r < 4; ++r)
                        Crow[(size_t)(row0 + r) * 512 + coll] =
                            __float2bfloat16(acc[i][j][r] + bv);
                } else {
                    u16x4 pk;
                    #pragma unroll
                    for (int r = 0; r < 4; ++r) {
                        float v = acc[i][j][r] + bv;
                        Crow[(size_t)(row0 + r) * 512 + coll] = __float2bfloat16(v);
                        pk[r] = f2bf_bits(v);
                    }
                    int hh = coll >> 6, dh = coll & 63;
                    int bb = row0 >> 11, s0 = row0 & 2047;
                    *(u16x4*)(CbT + ((size_t)((bb * 8 + hh) * 64 + dh) * 2048 + s0)) = pk;
                }
            }
        }
    } else {
        #pragma unroll
        for (int j = 0; j < 4; ++j) {
            int col = n0 + wn + j * 16 + il;
            float bv = bias0[col];
            #pragma unroll
            for (int i = 0; i < MI; ++i) {
                #pragma unroll
                for (int r = 0; r < 4; ++r) {
                    int row = m0 + wm + i * 16 + g * 4 + r;
                    float v = acc[i][j][r] + bv;
                    if (RELU) v = fmaxf(v, 0.0f);
                    if (OUT_MODE == 1) Cb0[(size_t)row * N + col] = __float2bfloat16(v);
                    else               Cf[(size_t)row * N + col] = v;
                }
            }
        }
    }
}

// ---------------------------------------------------------------------------
// MFMA block-sparse flash attention (v3).
// - local tiles {i0-64k}; diagonal tile skips jn>wv fragments (causal-dead);
// - global tile (j<16, only when i0>256): only s[0] computed (2 QK MFMAs),
//   P chunks 0-3 written (jn0 data + jn1 zeros), PV kh=0 only (4 MFMAs);
// - strided keys via per-lane diagonal dot phase;
// - s_setprio(1) around MFMA clusters; exp2-domain softmax; skip-rescale;
// - XCD swizzle clusters all 32 q-tiles of one (b,h) on one XCD.
// ---------------------------------------------------------------------------
__device__ __forceinline__ bf16x8 lds_frag(const unsigned short* base, int row, int chunk) {
    int byte = (row << 7) + (((chunk ^ (row & 7)) & 7) << 4);
    return *(const bf16x8*)((const char*)base + byte);
}

__global__ __launch_bounds__(256)
void attn_mfma_kernel(const __hip_bfloat16* __restrict__ Q,   // [NTOK][512]
                      const __hip_bfloat16* __restrict__ K,   // [NTOK][512]
                      const __hip_bfloat16* __restrict__ V,   // [NTOK][512]
                      const __hip_bfloat16* __restrict__ VT,  // [B*H*64][2048]
                      __hip_bfloat16* __restrict__ O) {       // [NTOK][512]
    __shared__ unsigned short Ks[2][64 * 64];
    __shared__ unsigned short Vs[2][64 * 64];
    __shared__ unsigned short Ps[4][16 * 64];

    // XCD swizzle: flat id -> (q, h, b) with q-tiles of one (b,h) contiguous per XCD
    int fid = blockIdx.x + 32 * (blockIdx.y + 8 * blockIdx.z);  // 0..1023
    int swz = (fid & 7) * 128 + (fid >> 3);
    int i0 = (swz & 31) * 64;
    int h  = (swz >> 5) & 7;
    int b  = swz >> 8;

    int tid = threadIdx.x, lane = tid & 63, wv = tid >> 6;
    int g = lane >> 4, il = lane & 15, g4 = g * 4;

    int nloc = min(i0 >> 6, 4) + 1;
    int add0 = (i0 > 256);
    int nt = nloc + add0;

    const size_t vt_off = (size_t)((b * 8 + h) * 64) * 2048;
    auto j0_of = [&](int t) { return (t < nloc) ? (i0 - 64 * t) : 0; };

    auto stage = [&](int buf, int j0) {
        #pragma unroll
        for (int q = 0; q < 2; ++q) {
            int idx = q * 256 + tid;
            int row = idx >> 3, c = idx & 7;
            int csw = c ^ (row & 7);
            const __hip_bfloat16* sk = K + (size_t)(b * 2048 + j0 + row) * 512 + h * 64 + csw * 8;
            __builtin_amdgcn_global_load_lds((gptr_u32)(const void*)sk,
                                             (lptr_u32)(void*)&Ks[buf][idx * 8], 16, 0, 0);
            const __hip_bfloat16* sv = VT + vt_off + (size_t)row * 2048 + j0 + csw * 8;
            __builtin_amdgcn_global_load_lds((gptr_u32)(const void*)sv,
                                             (lptr_u32)(void*)&Vs[buf][idx * 8], 16, 0, 0);
        }
    };

    int iq = i0 + wv * 16 + il;
    bf16x8 qf[2];
    #pragma unroll
    for (int kh = 0; kh < 2; ++kh)
        qf[kh] = *(const bf16x8*)(Q + (size_t)(b * 2048 + iq) * 512 + h * 64 + kh * 32 + g * 8);

    stage(0, j0_of(0));   // overlap first tile load with scalar phase

    float qfl[16];
    #pragma unroll
    for (int kh = 0; kh < 2; ++kh)
        #pragma unroll
        for (int e = 0; e < 8; ++e)
            qfl[kh * 8 + e] = bf2f(((u16x8)qf[kh])[e]);

    unsigned short* myP = Ps[wv];
    f32x4 o[4] = {};
    float os[16] = {};
    float m = -1e30f, l = 0.0f;
    const float CSC = 0.18033688011112042f; // 0.125 * log2(e)

    // ---- scalar strided phase ----
    const unsigned short* Kbase = (const unsigned short*)(K + (size_t)b * 2048 * 512 + h * 64);
    const unsigned short* Vbase = (const unsigned short*)(V + (size_t)b * 2048 * 512 + h * 64);
    for (int j = iq - 384; j >= 16; j -= 128) {
        const unsigned short* kr = Kbase + (size_t)j * 512;
        u16x8 k0 = *(const u16x8*)(kr + g * 8);
        u16x8 k1 = *(const u16x8*)(kr + 32 + g * 8);
        float dot = 0.0f;
        #pragma unroll
        for (int e = 0; e < 8; ++e)
            dot += qfl[e] * bf2f(k0[e]) + qfl[8 + e] * bf2f(k1[e]);
        dot += __shfl_xor(dot, 16);
        dot += __shfl_xor(dot, 32);
        float s2 = dot * CSC;
        float mn = fmaxf(m, s2);
        float al = exp2f(m - mn);
        float p = exp2f(s2 - mn);
        l = l * al + p;
        m = mn;
        const unsigned short* vr = Vbase + (size_t)j * 512;
        u16x8 v0 = *(const u16x8*)(vr + g * 8);
        u16x8 v1 = *(const u16x8*)(vr + 32 + g * 8);
        #pragma unroll
        for (int e = 0; e < 8; ++e) {
            os[e]     = os[e]     * al + p * bf2f(v0[e]);
            os[8 + e] = os[8 + e] * al + p * bf2f(v1[e]);
        }
    }

    // ---- MFMA tile phase ----
    for (int t = 0; t < nt; ++t) {
        __syncthreads();
        int cur = t & 1;
        if (t + 1 < nt) stage(cur ^ 1, j0_of(t + 1));
        int j0 = j0_of(t);
        bool gtile = (t >= nloc);
        bool dtile = (t == 0);

        f32x4 s[4] = {};
        __builtin_amdgcn_s_setprio(1);
        if (gtile) {
            #pragma unroll
            for (int kh = 0; kh < 2; ++kh) {
                bf16x8 a = lds_frag(Ks[cur], il, kh * 4 + g);
                s[0] = __builtin_amdgcn_mfma_f32_16x16x32_bf16(a, qf[kh], s[0], 0, 0, 0);
            }
        } else if (dtile) {
            #pragma unroll
            for (int kh = 0; kh < 2; ++kh)
                #pragma unroll
                for (int jn = 0; jn < 4; ++jn)
                    if (jn <= wv) {
                        bf16x8 a = lds_frag(Ks[cur], jn * 16 + il, kh * 4 + g);
                        s[jn] = __builtin_amdgcn_mfma_f32_16x16x32_bf16(a, qf[kh], s[jn], 0, 0, 0);
                    }
        } else {
            #pragma unroll
            for (int kh = 0; kh < 2; ++kh)
                #pragma unroll
                for (int jn = 0; jn < 4; ++jn) {
                    bf16x8 a = lds_frag(Ks[cur], jn * 16 + il, kh * 4 + g);
                    s[jn] = __builtin_amdgcn_mfma_f32_16x16x32_bf16(a, qf[kh], s[jn], 0, 0, 0);
                }
        }
        __builtin_amdgcn_s_setprio(0);

        // scale + mask + local max
        float mloc = -1e30f;
        if (gtile) {               // all 16 global keys allowed (iq >= 320 > 15)
            #pragma unroll
            for (int r = 0; r < 4; ++r) {
                float sv = s[0][r] * CSC;
                s[0][r] = sv;
                mloc = fmaxf(mloc, sv);
            }
        } else if (dtile) {        // diagonal: jn<wv all pass, jn==wv causal mask
            #pragma unroll
            for (int jn = 0; jn < 4; ++jn) {
                if (jn < wv) {
                    #pragma unroll
                    for (int r = 0; r < 4; ++r) {
                        float sv = s[jn][r] * CSC;
                        s[jn][r] = sv;
                        mloc = fmaxf(mloc, sv);
                    }
                } else if (jn == wv) {
                    #pragma unroll
                    for (int r = 0; r < 4; ++r) {
                        float sv = (g4 + r <= il) ? s[jn][r] * CSC : -1e30f;
                        s[jn][r] = sv;
                        mloc = fmaxf(mloc, sv);
                    }
                }
            }
        } else if (t == 4) {       // window edge: local | strided | global
            #pragma unroll
            for (int jn = 0; jn < 4; ++jn)
                #pragma unroll
                for (int r = 0; r < 4; ++r) {
                    int jg = j0 + jn * 16 + g4 + r;
                    int dij = iq - jg;
                    bool ok = (dij < 256) || ((dij & 127) == 0) || (jg < 16);
                    float sv = ok ? s[jn][r] * CSC : -1e30f;
                    s[jn][r] = sv;
                    mloc = fmaxf(mloc, sv);
                }
        } else {                   // fully inside window
            #pragma unroll
            for (int jn = 0; jn < 4; ++jn)
                #pragma unroll
                for (int r = 0; r < 4; ++r) {
                    float sv = s[jn][r] * CSC;
                    s[jn][r] = sv;
                    mloc = fmaxf(mloc, sv);
                }
        }
        mloc = fmaxf(mloc, __shfl_xor(mloc, 16));
        mloc = fmaxf(mloc, __shfl_xor(mloc, 32));
        float mn = fmaxf(m, mloc);
        float al = exp2f(m - mn);

        float lloc = 0.0f;
        if (gtile) {
            #pragma unroll
            for (int r = 0; r < 4; ++r) {
                float p = exp2f(s[0][r] - mn);
                s[0][r] = p;
                lloc += p;
            }
        } else {
            #pragma unroll
            for (int jn = 0; jn < 4; ++jn) {
                if (dtile && jn > wv) continue;
                #pragma unroll
                for (int r = 0; r < 4; ++r) {
                    float p = exp2f(s[jn][r] - mn);
                    s[jn][r] = p;
                    lloc += p;
                }
            }
        }
        lloc += __shfl_xor(lloc, 16);
        lloc += __shfl_xor(lloc, 32);
        l = l * al + lloc;
        m = mn;

        if (!__all(al == 1.0f)) {
            float ar[4];
            #pragma unroll
            for (int r = 0; r < 4; ++r) ar[r] = __shfl(al, g4 + r);
            #pragma unroll
            for (int dn = 0; dn < 4; ++dn)
                #pragma unroll
                for (int r = 0; r < 4; ++r) o[dn][r] *= ar[r];
            #pragma unroll
            for (int e = 0; e < 16; ++e) os[e] *= al;
        }

        // P -> LDS. chunk index of (jn,g) is jn*2 + (g>>1):
        //   gtile: jn0 data + jn1 zeros (chunks 0-3), skip jn2,3 (kh=1 skipped)
        //   dtile: zeros for jn>wv
        #pragma unroll
        for (int jn = 0; jn < 4; ++jn) {
            if (gtile && jn >= 2) continue;
            u16x4 pk = { 0, 0, 0, 0 };
            bool live = gtile ? (jn == 0) : (!dtile || jn <= wv);
            if (live) {
                #pragma unroll
                for (int r = 0; r < 4; ++r) pk[r] = f2bf_bits(s[jn][r]);
            }
            int byte = ((il << 7) + (jn << 5) + (g << 3)) ^ ((il & 7) << 4);
            *(u16x4*)((char*)myP + byte) = pk;
        }
        int khmax = (gtile || (dtile && wv < 2)) ? 1 : 2;
        __builtin_amdgcn_s_setprio(1);
        #pragma unroll
        for (int kh = 0; kh < 2; ++kh) {
            if (kh < khmax) {
                bf16x8 pa = lds_frag(myP, il, kh * 4 + g);
                #pragma unroll
                for (int dn = 0; dn < 4; ++dn) {
                    bf16x8 bv = lds_frag(Vs[cur], dn * 16 + il, kh * 4 + g);
                    o[dn] = __builtin_amdgcn_mfma_f32_16x16x32_bf16(pa, bv, o[dn], 0, 0, 0);
                }
            }
        }
        __builtin_amdgcn_s_setprio(0);
    }

    // ---- epilogue: merge os (row=il, dim split by g) with o fragment ----
    __syncthreads();
    float* osl = (float*)&Ks[0][0] + wv * 1024;  // 16 rows x 64 dims per wave
    #pragma unroll
    for (int kh = 0; kh < 2; ++kh)
        #pragma unroll
        for (int e = 0; e < 8; ++e)
            osl[il * 64 + kh * 32 + g * 8 + e] = os[kh * 8 + e];
    __syncthreads();

    float li[4];
    #pragma unroll
    for (int r = 0; r < 4; ++r) li[r] = 1.0f / __shfl(l, g4 + r);
    #pragma unroll
    for (int dn = 0; dn < 4; ++dn)
        #pragma unroll
        for (int r = 0; r < 4; ++r) {
            int row = i0 + wv * 16 + g4 + r;
            float add = osl[(g4 + r) * 64 + dn * 16 + il];
            O[(size_t)(b * 2048 + row) * 512 + h * 64 + dn * 16 + il] =
                __float2bfloat16((o[dn][r] + add) * li[r]);
        }
}

// ---------------------------------------------------------------------------
// Fused residual add + LayerNorm, vectorized: 4 rows/block (4 waves)
// ---------------------------------------------------------------------------
__global__ __launch_bounds__(256)
void add_ln_kernel(float* __restrict__ X,
                   const __hip_bfloat16* __restrict__ T,
                   const float* __restrict__ g,
                   const float* __restrict__ bb,
                   __hip_bfloat16* __restrict__ Xb) {
    size_t row = blockIdx.x * 4 + (threadIdx.x >> 6);
    int lane = threadIdx.x & 63;
    int d0 = lane * 8;
    float4 x0 = *(const float4*)(X + row * D_ + d0);
    float4 x1 = *(const float4*)(X + row * D_ + d0 + 4);
    u16x8 tv = *(const u16x8*)((const unsigned short*)T + row * D_ + d0);
    float v[8] = { x0.x + bf2f(tv[0]), x0.y + bf2f(tv[1]),
                   x0.z + bf2f(tv[2]), x0.w + bf2f(tv[3]),
                   x1.x + bf2f(tv[4]), x1.y + bf2f(tv[5]),
                   x1.z + bf2f(tv[6]), x1.w + bf2f(tv[7]) };
    float sum = 0.0f;
    #pragma unroll
    for (int q = 0; q < 8; ++q) sum += v[q];
    #pragma unroll
    for (int o = 32; o; o >>= 1) sum += __shfl_xor(sum, o);
    float mean = sum * (1.0f / D_);
    float var = 0.0f;
    #pragma unroll
    for (int q = 0; q < 8; ++q) { float dd = v[q] - mean; var += dd * dd; }
    #pragma unroll
    for (int o = 32; o; o >>= 1) var += __shfl_xor(var, o);
    var *= (1.0f / D_);
    float r = rsqrtf(var + 1e-5f);
    float4 g0 = *(const float4*)(g + d0),  g1 = *(const float4*)(g + d0 + 4);
    float4 b0 = *(const float4*)(bb + d0), b1 = *(const float4*)(bb + d0 + 4);
    float y[8];
    y[0] = (v[0]-mean)*r*g0.x+b0.x; y[1] = (v[1]-mean)*r*g0.y+b0.y;
    y[2] = (v[2]-mean)*r*g0.z+b0.z; y[3] = (v[3]-mean)*r*g0.w+b0.w;
    y[4] = (v[4]-mean)*r*g1.x+b1.x; y[5] = (v[5]-mean)*r*g1.y+b1.y;
    y[6] = (v[6]-mean)*r*g1.z+b1.z; y[7] = (v[7]-mean)*r*g1.w+b1.w;
    *(float4*)(X + row * D_ + d0)     = make_float4(y[0], y[1], y[2], y[3]);
    *(float4*)(X + row * D_ + d0 + 4) = make_float4(y[4], y[5], y[6], y[7]);
    u16x8 pk;
    #pragma unroll
    for (int q = 0; q < 8; ++q) pk[q] = f2bf_bits(y[q]);
    *(u16x8*)((unsigned short*)Xb + row * D_ + d0) = pk;
}

// ---------------------------------------------------------------------------
extern "C" void kernel_launch(void* const* d_in, const int* in_sizes, int n_in,
                              void* d_out, int out_size, void* d_ws, size_t ws_size,
                              hipStream_t stream) {
    const int*   tok   = (const int*)  d_in[0];
    const float* emb   = (const float*)d_in[1];
    const float* b_out = (const float*)d_in[2];
    const float* Wq    = (const float*)d_in[3];
    const float* bq    = (const float*)d_in[4];
    const float* Wk    = (const float*)d_in[5];
    const float* bk    = (const float*)d_in[6];
    const float* Wv    = (const float*)d_in[7];
    const float* bv    = (const float*)d_in[8];
    const float* Wo    = (const float*)d_in[9];
    const float* bo    = (const float*)d_in[10];
    const float* ln1g  = (const float*)d_in[11];
    const float* ln1b  = (const float*)d_in[12];
    const float* W1    = (const float*)d_in[13];
    const float* b1    = (const float*)d_in[14];
    const float* W2    = (const float*)d_in[15];
    const float* b2    = (const float*)d_in[16];
    const float* ln2g  = (const float*)d_in[17];
    const float* ln2b  = (const float*)d_in[18];
    float* out = (float*)d_out;

    char* w = (char*)d_ws;
    auto alloc = [&](size_t bytes) {
        char* p = w;
        w += (bytes + 255) & ~(size_t)255;
        return p;
    };
    float*          X   = (float*)         alloc(XN * 4);
    __hip_bfloat16* Xb  = (__hip_bfloat16*)alloc(XN * 2);
    __hip_bfloat16* Tb  = (__hip_bfloat16*)alloc(XN * 2);
    char* uni = alloc(XN * 2 * 5);
    __hip_bfloat16* Qb  = (__hip_bfloat16*)uni;
    __hip_bfloat16* Kb  = Qb + XN;
    __hip_bfloat16* Vb  = Kb + XN;
    __hip_bfloat16* VTb = Vb + XN;   // [B,H,64,S]
    __hip_bfloat16* Ob  = VTb + XN;
    __hip_bfloat16* Hb  = (__hip_bfloat16*)uni;      // [NTOK, FF] (reuses Qb..VTb)
    __hip_bfloat16* Wqkvt = (__hip_bfloat16*)alloc((size_t)L_ * 1536 * D_ * 2);
    __hip_bfloat16* Wot  = (__hip_bfloat16*)alloc((size_t)L_ * D_ * D_ * 2);
    __hip_bfloat16* W1t  = (__hip_bfloat16*)alloc((size_t)L_ * D_ * FF_ * 2);
    __hip_bfloat16* W2t  = (__hip_bfloat16*)alloc((size_t)L_ * FF_ * D_ * 2);
    __hip_bfloat16* embb = (__hip_bfloat16*)alloc((size_t)V_ * D_ * 2);
    float*          PE   = (float*)alloc((size_t)S_ * D_ * 4);

    // ---- prep ----
    {
        pe_table_kernel<<<S_, 256, 0, stream>>>(PE);
        dim3 gqkv(D_ / 32, D_ / 32, L_ * 3);
        transpose_qkv_kernel<<<gqkv, 256, 0, stream>>>(Wq, Wk, Wv, Wqkvt);
        dim3 gdd(D_ / 32, D_ / 32, L_);
        transpose_conv_kernel<<<gdd, 256, 0, stream>>>(Wo, Wot, D_, D_);
        dim3 g1(FF_ / 32, D_ / 32, L_);
        transpose_conv_kernel<<<g1, 256, 0, stream>>>(W1, W1t, D_, FF_);
        dim3 g2(D_ / 32, FF_ / 32, L_);
        transpose_conv_kernel<<<g2, 256, 0, stream>>>(W2, W2t, FF_, D_);
        conv_bf16_kernel<<<(V_ * D_ + 255) / 256, 256, 0, stream>>>(emb, embb, V_ * D_);
    }

    embed_kernel<<<NTOK, 128, 0, stream>>>(tok, emb, PE, X, Xb);

    dim3 blk(256);
    dim3 gqkv(1536 / 128, NTOK / 128);      // 12 x 64 = 768 blocks, BM=128
    dim3 g512n(D_ / 128, NTOK / 64);        // 4 x 128 = 512 blocks, BM=64
    dim3 gff (FF_ / 128, NTOK / 128);       // 16 x 64 = 1024 blocks, BM=128
    dim3 gout(V_ / 128, NTOK / 64);         // 2 x 128 = 256 blocks, BM=64
    dim3 gattn(S_ / 64, H_, B_);
    dim3 gln(NTOK / 4);

    for (int l = 0; l < L_; ++l) {
        const __hip_bfloat16* wqkv = Wqkvt + (size_t)l * 1536 * D_;
        const __hip_bfloat16* wot = Wot + (size_t)l * D_ * D_;
        const __hip_bfloat16* w1t = W1t + (size_t)l * D_ * FF_;
        const __hip_bfloat16* w2t = W2t + (size_t)l * FF_ * D_;

        gemm_bf16_kernel<128, 0, 4><<<gqkv, blk, 0, stream>>>(
            Xb, wqkv, bq + l * D_, bk + l * D_, bv + l * D_,
            nullptr, Qb, Kb, Vb, VTb, NTOK, 1536, D_);

        attn_mfma_kernel<<<gattn, blk, 0, stream>>>(Qb, Kb, Vb, VTb, Ob);

        gemm_bf16_kernel<64, 0, 1><<<g512n, blk, 0, stream>>>(
            Ob, wot, bo + l * D_, nullptr, nullptr,
            nullptr, Tb, nullptr, nullptr, nullptr, NTOK, D_, D_);
        add_ln_kernel<<<gln, blk, 0, stream>>>(X, Tb, ln1g + l * D_, ln1b + l * D_, Xb);

        gemm_bf16_kernel<128, 1, 1><<<gff, blk, 0, stream>>>(
            Xb, w1t, b1 + l * FF_, nullptr, nullptr,
            nullptr, Hb, nullptr, nullptr, nullptr, NTOK, FF_, D_);
        gemm_bf16_kernel<64, 0, 1><<<g512n, blk, 0, stream>>>(
            Hb, w2t, b2 + l * D_, nullptr, nullptr,
            nullptr, Tb, nullptr, nullptr, nullptr, NTOK, D_, FF_);
        add_ln_kernel<<<gln, blk, 0, stream>>>(X, Tb, ln2g + l * D_, ln2b + l * D_, Xb);
    }

    gemm_bf16_kernel<64, 0, 0><<<gout, blk, 0, stream>>>(
        Xb, embb, b_out, nullptr, nullptr,
        out, nullptr, nullptr, nullptr, nullptr, NTOK, V_, D_);
}